// Round 1
// baseline (525.661 us; speedup 1.0000x reference)
//
#include <hip/hip_runtime.h>

#define B_ 8192
#define IN_ 1024
#define OUT_ 256
#define E_ 16
#define KTOP 3
#define H_ 512
#define MAXSLOTS 26624   // 24576 + 16*127 rounded up to 128-multiple capacity
#define NTILES 208       // MAXSLOTS / 128

typedef __bf16 bf16;
typedef __bf16 bf16x4 __attribute__((ext_vector_type(4)));
typedef __bf16 bf16x8 __attribute__((ext_vector_type(8)));
typedef float f32x4 __attribute__((ext_vector_type(4)));

// async global->LDS, 16B per lane. LDS dest must be wave-uniform base + lane*16.
__device__ __forceinline__ void async16(const bf16* g, bf16* l) {
    __builtin_amdgcn_global_load_lds(
        (const __attribute__((address_space(1))) void*)g,
        (__attribute__((address_space(3))) void*)l,
        16, 0, 0);
}

// ---------------- init ----------------
__global__ __launch_bounds__(256) void k_init(
    float* __restrict__ y, int* __restrict__ row_ids, float* __restrict__ slot_gate,
    int* __restrict__ tile_expert, int* __restrict__ counts, int* __restrict__ fill,
    float* __restrict__ importance, bf16* __restrict__ zero_row) {
    int id = blockIdx.x * 256 + threadIdx.x;
    if (id < B_ * OUT_) y[id] = 0.f;
    if (id < MAXSLOTS) { row_ids[id] = -1; slot_gate[id] = 0.f; }
    if (id < NTILES) tile_expert[id] = -1;
    if (id < E_) { counts[id] = 0; fill[id] = 0; importance[id] = 0.f; }
    if (id < IN_) zero_row[id] = (bf16)0.f;
}

// ---------------- transpose+convert weights: in [E][K][N] f32 -> out [E][N][K] bf16 ----------------
__global__ __launch_bounds__(256) void k_transpose(
    const float* __restrict__ in, bf16* __restrict__ out, int Kd, int Nd) {
    __shared__ float tile[64][65];
    int e = blockIdx.y;
    int ntn = Nd >> 6;
    int tk = blockIdx.x / ntn, tn = blockIdx.x % ntn;
    int t = threadIdx.x;
    int r = t >> 6, c = t & 63;
    const float* src = in + ((size_t)e * Kd + tk * 64) * Nd + (size_t)tn * 64;
#pragma unroll
    for (int i = 0; i < 16; i++) {
        int rr = r + i * 4;
        tile[rr][c] = src[(size_t)rr * Nd + c];
    }
    __syncthreads();
    bf16* dst = out + ((size_t)e * Nd + tn * 64) * Kd + (size_t)tk * 64;
#pragma unroll
    for (int i = 0; i < 16; i++) {
        int rr = r + i * 4;
        dst[(size_t)rr * Kd + c] = (bf16)tile[c][rr];
    }
}

// ---------------- gating: logits, top-3 softmax, counts; also emit x in bf16 ----------------
__global__ __launch_bounds__(256) void k_gating(
    const float* __restrict__ x, const float* __restrict__ wg,
    bf16* __restrict__ xbf, int* __restrict__ top_idx, float* __restrict__ top_gate,
    int* __restrict__ counts) {
    int t = threadIdx.x;
    int row = blockIdx.x * 4 + (t >> 6);
    int lane = t & 63;
    float acc[16];
#pragma unroll
    for (int e = 0; e < 16; e++) acc[e] = 0.f;
    const float4* x4p = (const float4*)(x + (size_t)row * IN_);
    const float4* wg4 = (const float4*)wg;
    for (int j0 = lane; j0 < IN_ / 4; j0 += 64) {
        float4 xv = x4p[j0];
        bf16x4 xb;
        xb[0] = (bf16)xv.x; xb[1] = (bf16)xv.y; xb[2] = (bf16)xv.z; xb[3] = (bf16)xv.w;
        *(bf16x4*)(xbf + (size_t)row * IN_ + j0 * 4) = xb;
        float xs[4] = {xv.x, xv.y, xv.z, xv.w};
#pragma unroll
        for (int i = 0; i < 4; i++) {
            int jb = (j0 * 4 + i) * 4;  // float4 index into wg row
#pragma unroll
            for (int q = 0; q < 4; q++) {
                float4 wv = wg4[jb + q];
                acc[q * 4 + 0] += xs[i] * wv.x;
                acc[q * 4 + 1] += xs[i] * wv.y;
                acc[q * 4 + 2] += xs[i] * wv.z;
                acc[q * 4 + 3] += xs[i] * wv.w;
            }
        }
    }
#pragma unroll
    for (int e = 0; e < 16; e++) {
#pragma unroll
        for (int s = 32; s > 0; s >>= 1) acc[e] += __shfl_xor(acc[e], s, 64);
    }
    if (lane == 0) {
        float v[16];
#pragma unroll
        for (int e = 0; e < 16; e++) v[e] = acc[e];
        int idx[KTOP];
        float val[KTOP];
#pragma unroll
        for (int k = 0; k < KTOP; k++) {
            int best = 0;
            float bv = v[0];
            for (int e = 1; e < 16; e++) {
                if (v[e] > bv) { bv = v[e]; best = e; }
            }
            idx[k] = best; val[k] = bv; v[best] = -1e30f;
        }
        // softmax over top-3 (val[0] is max)
        float e0 = __expf(0.f);
        float e1 = __expf(val[1] - val[0]);
        float e2 = __expf(val[2] - val[0]);
        float inv = 1.f / (e0 + e1 + e2);
        float g[KTOP] = {e0 * inv, e1 * inv, e2 * inv};
#pragma unroll
        for (int k = 0; k < KTOP; k++) {
            top_idx[row * KTOP + k] = idx[k];
            top_gate[row * KTOP + k] = g[k];
            atomicAdd(&counts[idx[k]], 1);
        }
    }
}

// ---------------- scan: padded per-expert offsets + tile->expert map ----------------
__global__ void k_scan(const int* __restrict__ counts, int* __restrict__ offsets,
                       int* __restrict__ tile_expert) {
    if (threadIdx.x == 0 && blockIdx.x == 0) {
        int off = 0;
        for (int e = 0; e < E_; e++) {
            offsets[e] = off;
            int p = (counts[e] + 127) & ~127;
            int t0 = off >> 7, t1 = (off + p) >> 7;
            for (int tt = t0; tt < t1; ++tt) tile_expert[tt] = e;
            off += p;
        }
        offsets[E_] = off;
    }
}

// ---------------- scatter: assign slots, accumulate importance ----------------
__global__ __launch_bounds__(256) void k_scatter(
    const int* __restrict__ top_idx, const float* __restrict__ top_gate,
    const int* __restrict__ offsets, int* __restrict__ fill,
    int* __restrict__ row_ids, float* __restrict__ slot_gate,
    float* __restrict__ importance) {
    __shared__ int lcnt[16];
    __shared__ int lbase[16];
    __shared__ float limp[16];
    int t = threadIdx.x;
    if (t < 16) { lcnt[t] = 0; limp[t] = 0.f; }
    __syncthreads();
    int gid = blockIdx.x * 256 + t;  // [0, 24576)
    int e = top_idx[gid];
    float g = top_gate[gid];
    int lpos = atomicAdd(&lcnt[e], 1);
    atomicAdd(&limp[e], g);
    __syncthreads();
    if (t < 16) {
        lbase[t] = (lcnt[t] > 0) ? atomicAdd(&fill[t], lcnt[t]) : 0;
        if (limp[t] != 0.f) atomicAdd(&importance[t], limp[t]);
    }
    __syncthreads();
    int slot = offsets[e] + lbase[e] + lpos;
    row_ids[slot] = gid / KTOP;
    slot_gate[slot] = g;
}

// ---------------- GEMM1: h = relu(gather(x) @ W1[e] + b1[e]) -> bf16 ----------------
__global__ __launch_bounds__(256) void k_gemm1(
    const bf16* __restrict__ xbf, const bf16* __restrict__ w1t,
    const float* __restrict__ b1, const int* __restrict__ row_ids,
    const int* __restrict__ tile_expert, const bf16* __restrict__ zero_row,
    bf16* __restrict__ h) {
    int e = tile_expert[blockIdx.x];
    if (e < 0) return;
    int slot_base = blockIdx.x * 128;
    int nbase = blockIdx.y * 128;
    __shared__ __align__(16) bf16 As[128 * 32];  // [m][k]
    __shared__ __align__(16) bf16 Bs[128 * 32];  // [n][k]
    int t = threadIdx.x;
    int m0 = t >> 2, kc = (t & 3) * 8;
    int m1 = m0 + 64;
    int r0 = row_ids[slot_base + m0];
    int r1 = row_ids[slot_base + m1];
    const bf16* ga0 = (r0 >= 0) ? xbf + (size_t)r0 * IN_ + kc : zero_row + kc;
    const bf16* ga1 = (r1 >= 0) ? xbf + (size_t)r1 * IN_ + kc : zero_row + kc;
    const bf16* gb0 = w1t + ((size_t)e * H_ + nbase + m0) * IN_ + kc;
    const bf16* gb1 = w1t + ((size_t)e * H_ + nbase + m1) * IN_ + kc;
    int w = t >> 6, lane = t & 63;
    int wm = (w >> 1) * 64, wn = (w & 1) * 64;
    int lm = lane & 15, lq = lane >> 4;
    f32x4 acc[4][4] = {};
    for (int k0 = 0; k0 < IN_; k0 += 32) {
        async16(ga0 + k0, As + t * 8);
        async16(ga1 + k0, As + (t + 256) * 8);
        async16(gb0 + k0, Bs + t * 8);
        async16(gb1 + k0, Bs + (t + 256) * 8);
        __syncthreads();
        const bf16x8* Av = (const bf16x8*)As;
        const bf16x8* Bv = (const bf16x8*)Bs;
        bf16x8 af[4], bfv[4];
#pragma unroll
        for (int i = 0; i < 4; i++) af[i] = Av[(wm + i * 16 + lm) * 4 + lq];
#pragma unroll
        for (int i = 0; i < 4; i++) bfv[i] = Bv[(wn + i * 16 + lm) * 4 + lq];
#pragma unroll
        for (int mi = 0; mi < 4; mi++)
#pragma unroll
            for (int ni = 0; ni < 4; ni++)
                acc[mi][ni] = __builtin_amdgcn_mfma_f32_16x16x32_bf16(af[mi], bfv[ni], acc[mi][ni], 0, 0, 0);
        __syncthreads();
    }
#pragma unroll
    for (int mi = 0; mi < 4; mi++) {
#pragma unroll
        for (int ni = 0; ni < 4; ni++) {
            int colg = nbase + wn + ni * 16 + lm;
            float bias = b1[e * H_ + colg];
#pragma unroll
            for (int r = 0; r < 4; r++) {
                int rowl = wm + mi * 16 + lq * 4 + r;
                float v = acc[mi][ni][r] + bias;
                v = v > 0.f ? v : 0.f;
                h[(size_t)(slot_base + rowl) * H_ + colg] = (bf16)v;
            }
        }
    }
}

// ---------------- GEMM2: y[row] += gate * (h @ W2[e] + b2[e]) ----------------
__global__ __launch_bounds__(256) void k_gemm2(
    const bf16* __restrict__ h, const bf16* __restrict__ w2t,
    const float* __restrict__ b2, const int* __restrict__ row_ids,
    const float* __restrict__ slot_gate, const int* __restrict__ tile_expert,
    float* __restrict__ y) {
    int e = tile_expert[blockIdx.x];
    if (e < 0) return;
    int slot_base = blockIdx.x * 128;
    int nbase = blockIdx.y * 128;
    __shared__ __align__(16) bf16 As[128 * 32];
    __shared__ __align__(16) bf16 Bs[128 * 32];
    int t = threadIdx.x;
    int m0 = t >> 2, kc = (t & 3) * 8;
    int m1 = m0 + 64;
    const bf16* ga0 = h + (size_t)(slot_base + m0) * H_ + kc;
    const bf16* ga1 = h + (size_t)(slot_base + m1) * H_ + kc;
    const bf16* gb0 = w2t + ((size_t)e * OUT_ + nbase + m0) * H_ + kc;
    const bf16* gb1 = w2t + ((size_t)e * OUT_ + nbase + m1) * H_ + kc;
    int w = t >> 6, lane = t & 63;
    int wm = (w >> 1) * 64, wn = (w & 1) * 64;
    int lm = lane & 15, lq = lane >> 4;
    f32x4 acc[4][4] = {};
    for (int k0 = 0; k0 < H_; k0 += 32) {
        async16(ga0 + k0, As + t * 8);
        async16(ga1 + k0, As + (t + 256) * 8);
        async16(gb0 + k0, Bs + t * 8);
        async16(gb1 + k0, Bs + (t + 256) * 8);
        __syncthreads();
        const bf16x8* Av = (const bf16x8*)As;
        const bf16x8* Bv = (const bf16x8*)Bs;
        bf16x8 af[4], bfv[4];
#pragma unroll
        for (int i = 0; i < 4; i++) af[i] = Av[(wm + i * 16 + lm) * 4 + lq];
#pragma unroll
        for (int i = 0; i < 4; i++) bfv[i] = Bv[(wn + i * 16 + lm) * 4 + lq];
#pragma unroll
        for (int mi = 0; mi < 4; mi++)
#pragma unroll
            for (int ni = 0; ni < 4; ni++)
                acc[mi][ni] = __builtin_amdgcn_mfma_f32_16x16x32_bf16(af[mi], bfv[ni], acc[mi][ni], 0, 0, 0);
        __syncthreads();
    }
#pragma unroll
    for (int mi = 0; mi < 4; mi++) {
#pragma unroll
        for (int ni = 0; ni < 4; ni++) {
            int colg = nbase + wn + ni * 16 + lm;
            float bias = b2[e * OUT_ + colg];
#pragma unroll
            for (int r = 0; r < 4; r++) {
                int rowl = wm + mi * 16 + lq * 4 + r;
                int slot = slot_base + rowl;
                int rid = row_ids[slot];
                if (rid >= 0) {
                    float g = slot_gate[slot];
                    atomicAdd(&y[(size_t)rid * OUT_ + colg], g * (acc[mi][ni][r] + bias));
                }
            }
        }
    }
}

// ---------------- loss: cv^2(importance) + cv^2(load), ddof=1 ----------------
__global__ void k_loss(const float* __restrict__ importance, const int* __restrict__ counts,
                       float* __restrict__ loss_out) {
    if (threadIdx.x == 0 && blockIdx.x == 0) {
        float si = 0.f, sl = 0.f;
        for (int e = 0; e < E_; e++) { si += importance[e]; sl += (float)counts[e]; }
        float mi_ = si / (float)E_, ml_ = sl / (float)E_;
        float vi = 0.f, vl = 0.f;
        for (int e = 0; e < E_; e++) {
            float d = importance[e] - mi_; vi += d * d;
            float d2 = (float)counts[e] - ml_; vl += d2 * d2;
        }
        vi /= (float)(E_ - 1); vl /= (float)(E_ - 1);
        *loss_out = vi / (mi_ * mi_ + 1e-10f) + vl / (ml_ * ml_ + 1e-10f);
    }
}

extern "C" void kernel_launch(void* const* d_in, const int* in_sizes, int n_in,
                              void* d_out, int out_size, void* d_ws, size_t ws_size,
                              hipStream_t stream) {
    (void)in_sizes; (void)n_in; (void)out_size; (void)ws_size;
    const float* x = (const float*)d_in[0];
    const float* wgate = (const float*)d_in[1];
    const float* W1 = (const float*)d_in[2];
    const float* b1 = (const float*)d_in[3];
    const float* W2 = (const float*)d_in[4];
    const float* b2 = (const float*)d_in[5];
    float* y = (float*)d_out;  // [B*OUT] floats, then loss scalar at [B*OUT]

    char* p = (char*)d_ws;
    auto alloc = [&](size_t bytes) {
        char* q = p;
        p += (bytes + 255) & ~(size_t)255;
        return q;
    };
    bf16* xbf = (bf16*)alloc((size_t)B_ * IN_ * 2);          // 16 MB
    bf16* w1t = (bf16*)alloc((size_t)E_ * H_ * IN_ * 2);     // 16 MB  [E][H][IN]
    bf16* w2t = (bf16*)alloc((size_t)E_ * OUT_ * H_ * 2);    // 4 MB   [E][OUT][H]
    bf16* h = (bf16*)alloc((size_t)MAXSLOTS * H_ * 2);       // 27 MB
    int* row_ids = (int*)alloc((size_t)MAXSLOTS * 4);
    float* slot_gate = (float*)alloc((size_t)MAXSLOTS * 4);
    int* top_idx = (int*)alloc((size_t)B_ * KTOP * 4);
    float* top_gate = (float*)alloc((size_t)B_ * KTOP * 4);
    int* counts = (int*)alloc(E_ * 4);
    int* fill = (int*)alloc(E_ * 4);
    int* offsets = (int*)alloc((E_ + 1) * 4);
    int* tile_expert = (int*)alloc(NTILES * 4);
    float* importance = (float*)alloc(E_ * 4);
    bf16* zero_row = (bf16*)alloc(IN_ * 2);

    k_init<<<dim3((B_ * OUT_) / 256), dim3(256), 0, stream>>>(
        y, row_ids, slot_gate, tile_expert, counts, fill, importance, zero_row);
    k_transpose<<<dim3((IN_ / 64) * (H_ / 64), E_), dim3(256), 0, stream>>>(W1, w1t, IN_, H_);
    k_transpose<<<dim3((H_ / 64) * (OUT_ / 64), E_), dim3(256), 0, stream>>>(W2, w2t, H_, OUT_);
    k_gating<<<dim3(B_ / 4), dim3(256), 0, stream>>>(x, wgate, xbf, top_idx, top_gate, counts);
    k_scan<<<dim3(1), dim3(64), 0, stream>>>(counts, offsets, tile_expert);
    k_scatter<<<dim3((B_ * KTOP) / 256), dim3(256), 0, stream>>>(
        top_idx, top_gate, offsets, fill, row_ids, slot_gate, importance);
    k_gemm1<<<dim3(NTILES, H_ / 128), dim3(256), 0, stream>>>(
        xbf, w1t, b1, row_ids, tile_expert, zero_row, h);
    k_gemm2<<<dim3(NTILES, OUT_ / 128), dim3(256), 0, stream>>>(
        h, w2t, b2, row_ids, slot_gate, tile_expert, y);
    k_loss<<<dim3(1), dim3(64), 0, stream>>>(importance, counts, y + (size_t)B_ * OUT_);
}

// Round 2
// 322.255 us; speedup vs baseline: 1.6312x; 1.6312x over previous
//
#include <hip/hip_runtime.h>

#define B_ 8192
#define IN_ 1024
#define OUT_ 256
#define E_ 16
#define KTOP 3
#define H_ 512
#define MAXSLOTS 26624   // 24576 + 16*127 rounded up to 128-multiple capacity
#define NTILES 208       // MAXSLOTS / 128

typedef __bf16 bf16;
typedef __bf16 bf16x4 __attribute__((ext_vector_type(4)));
typedef __bf16 bf16x8 __attribute__((ext_vector_type(8)));
typedef float f32x4 __attribute__((ext_vector_type(4)));

// async global->LDS, 16B per lane. LDS dest must be wave-uniform base + lane*16.
__device__ __forceinline__ void async16(const bf16* g, bf16* l) {
    __builtin_amdgcn_global_load_lds(
        (const __attribute__((address_space(1))) void*)g,
        (__attribute__((address_space(3))) void*)l,
        16, 0, 0);
}

// ---------------- init ----------------
__global__ __launch_bounds__(256) void k_init(
    float* __restrict__ y, int* __restrict__ row_ids, float* __restrict__ slot_gate,
    int* __restrict__ tile_expert, int* __restrict__ fill,
    float* __restrict__ importance, bf16* __restrict__ zero_row) {
    int id = blockIdx.x * 256 + threadIdx.x;
    if (id < B_ * OUT_) y[id] = 0.f;
    if (id < MAXSLOTS) { row_ids[id] = -1; slot_gate[id] = 0.f; }
    if (id < NTILES) tile_expert[id] = -1;
    if (id < E_) { fill[id] = 0; importance[id] = 0.f; }
    if (id < IN_) zero_row[id] = (bf16)0.f;
}

// ---------------- transpose+convert weights: in [E][K][N] f32 -> out [E][N][K] bf16 ----------------
__global__ __launch_bounds__(256) void k_transpose(
    const float* __restrict__ in, bf16* __restrict__ out, int Kd, int Nd) {
    __shared__ float tile[64][65];
    int e = blockIdx.y;
    int ntn = Nd >> 6;
    int tk = blockIdx.x / ntn, tn = blockIdx.x % ntn;
    int t = threadIdx.x;
    int r = t >> 6, c = t & 63;
    const float* src = in + ((size_t)e * Kd + tk * 64) * Nd + (size_t)tn * 64;
#pragma unroll
    for (int i = 0; i < 16; i++) {
        int rr = r + i * 4;
        tile[rr][c] = src[(size_t)rr * Nd + c];
    }
    __syncthreads();
    bf16* dst = out + ((size_t)e * Nd + tn * 64) * Kd + (size_t)tk * 64;
#pragma unroll
    for (int i = 0; i < 16; i++) {
        int rr = r + i * 4;
        dst[(size_t)rr * Kd + c] = (bf16)tile[c][rr];
    }
}

// ---------------- gating: logits, top-3 softmax; also emit x in bf16 (NO atomics) ----------------
__global__ __launch_bounds__(256) void k_gating(
    const float* __restrict__ x, const float* __restrict__ wg,
    bf16* __restrict__ xbf, int* __restrict__ top_idx, float* __restrict__ top_gate) {
    int t = threadIdx.x;
    int row = blockIdx.x * 4 + (t >> 6);
    int lane = t & 63;
    float acc[16];
#pragma unroll
    for (int e = 0; e < 16; e++) acc[e] = 0.f;
    const float4* x4p = (const float4*)(x + (size_t)row * IN_);
    const float4* wg4 = (const float4*)wg;
    for (int j0 = lane; j0 < IN_ / 4; j0 += 64) {
        float4 xv = x4p[j0];
        bf16x4 xb;
        xb[0] = (bf16)xv.x; xb[1] = (bf16)xv.y; xb[2] = (bf16)xv.z; xb[3] = (bf16)xv.w;
        *(bf16x4*)(xbf + (size_t)row * IN_ + j0 * 4) = xb;
        float xs[4] = {xv.x, xv.y, xv.z, xv.w};
#pragma unroll
        for (int i = 0; i < 4; i++) {
            int jb = (j0 * 4 + i) * 4;  // float4 index into wg row
#pragma unroll
            for (int q = 0; q < 4; q++) {
                float4 wv = wg4[jb + q];
                acc[q * 4 + 0] += xs[i] * wv.x;
                acc[q * 4 + 1] += xs[i] * wv.y;
                acc[q * 4 + 2] += xs[i] * wv.z;
                acc[q * 4 + 3] += xs[i] * wv.w;
            }
        }
    }
#pragma unroll
    for (int e = 0; e < 16; e++) {
#pragma unroll
        for (int s = 32; s > 0; s >>= 1) acc[e] += __shfl_xor(acc[e], s, 64);
    }
    if (lane == 0) {
        float v[16];
#pragma unroll
        for (int e = 0; e < 16; e++) v[e] = acc[e];
        int idx[KTOP];
        float val[KTOP];
#pragma unroll
        for (int k = 0; k < KTOP; k++) {
            int best = 0;
            float bv = v[0];
            for (int e = 1; e < 16; e++) {
                if (v[e] > bv) { bv = v[e]; best = e; }
            }
            idx[k] = best; val[k] = bv; v[best] = -1e30f;
        }
        // softmax over top-3 (val[0] is max)
        float e1 = __expf(val[1] - val[0]);
        float e2 = __expf(val[2] - val[0]);
        float inv = 1.f / (1.f + e1 + e2);
        float g[KTOP] = {inv, e1 * inv, e2 * inv};
#pragma unroll
        for (int k = 0; k < KTOP; k++) {
            top_idx[row * KTOP + k] = idx[k];
            top_gate[row * KTOP + k] = g[k];
        }
    }
}

// ---------------- hist + scan: ballot histogram (no atomics), offsets, tile map ----------------
__global__ __launch_bounds__(256) void k_hist_scan(
    const int* __restrict__ top_idx, int* __restrict__ counts,
    int* __restrict__ offsets, int* __restrict__ tile_expert) {
    __shared__ int wcnt[4][16];
    int t = threadIdx.x;
    int w = t >> 6, lane = t & 63;
    int cnt[16];
#pragma unroll
    for (int k = 0; k < 16; k++) cnt[k] = 0;
    for (int i = t; i < B_ * KTOP; i += 256) {
        int e = top_idx[i];
#pragma unroll
        for (int k = 0; k < 16; k++)
            cnt[k] += (int)__popcll(__ballot(e == k));
    }
    if (lane == 0) {
#pragma unroll
        for (int k = 0; k < 16; k++) wcnt[w][k] = cnt[k];
    }
    __syncthreads();
    if (t == 0) {
        int off = 0;
        for (int e = 0; e < E_; e++) {
            int c = wcnt[0][e] + wcnt[1][e] + wcnt[2][e] + wcnt[3][e];
            counts[e] = c;
            offsets[e] = off;
            int p = (c + 127) & ~127;
            int t0 = off >> 7, t1 = (off + p) >> 7;
            for (int tt = t0; tt < t1; ++tt) tile_expert[tt] = e;
            off += p;
        }
        offsets[E_] = off;
    }
}

// ---------------- scatter: assign slots, accumulate importance ----------------
__global__ __launch_bounds__(256) void k_scatter(
    const int* __restrict__ top_idx, const float* __restrict__ top_gate,
    const int* __restrict__ offsets, int* __restrict__ fill,
    int* __restrict__ row_ids, float* __restrict__ slot_gate,
    float* __restrict__ importance) {
    __shared__ int lcnt[16];
    __shared__ int lbase[16];
    __shared__ float limp[16];
    int t = threadIdx.x;
    if (t < 16) { lcnt[t] = 0; limp[t] = 0.f; }
    __syncthreads();
    int gid = blockIdx.x * 256 + t;  // [0, 24576)
    int e = top_idx[gid];
    float g = top_gate[gid];
    int lpos = atomicAdd(&lcnt[e], 1);
    atomicAdd(&limp[e], g);
    __syncthreads();
    if (t < 16) {
        lbase[t] = (lcnt[t] > 0) ? atomicAdd(&fill[t], lcnt[t]) : 0;
        if (limp[t] != 0.f) atomicAdd(&importance[t], limp[t]);
    }
    __syncthreads();
    int slot = offsets[e] + lbase[e] + lpos;
    row_ids[slot] = gid / KTOP;
    slot_gate[slot] = g;
}

// ---------------- GEMM1: h = relu(gather(x) @ W1[e] + b1[e]) -> bf16 ----------------
__global__ __launch_bounds__(256) void k_gemm1(
    const bf16* __restrict__ xbf, const bf16* __restrict__ w1t,
    const float* __restrict__ b1, const int* __restrict__ row_ids,
    const int* __restrict__ tile_expert, const bf16* __restrict__ zero_row,
    bf16* __restrict__ h) {
    int e = tile_expert[blockIdx.x];
    if (e < 0) return;
    int slot_base = blockIdx.x * 128;
    int nbase = blockIdx.y * 128;
    __shared__ __align__(16) bf16 As[128 * 32];  // [m][k]
    __shared__ __align__(16) bf16 Bs[128 * 32];  // [n][k]
    int t = threadIdx.x;
    int m0 = t >> 2, kc = (t & 3) * 8;
    int m1 = m0 + 64;
    int r0 = row_ids[slot_base + m0];
    int r1 = row_ids[slot_base + m1];
    const bf16* ga0 = (r0 >= 0) ? xbf + (size_t)r0 * IN_ + kc : zero_row + kc;
    const bf16* ga1 = (r1 >= 0) ? xbf + (size_t)r1 * IN_ + kc : zero_row + kc;
    const bf16* gb0 = w1t + ((size_t)e * H_ + nbase + m0) * IN_ + kc;
    const bf16* gb1 = w1t + ((size_t)e * H_ + nbase + m1) * IN_ + kc;
    int w = t >> 6, lane = t & 63;
    int wm = (w >> 1) * 64, wn = (w & 1) * 64;
    int lm = lane & 15, lq = lane >> 4;
    f32x4 acc[4][4] = {};
    for (int k0 = 0; k0 < IN_; k0 += 32) {
        async16(ga0 + k0, As + t * 8);
        async16(ga1 + k0, As + (t + 256) * 8);
        async16(gb0 + k0, Bs + t * 8);
        async16(gb1 + k0, Bs + (t + 256) * 8);
        __syncthreads();
        const bf16x8* Av = (const bf16x8*)As;
        const bf16x8* Bv = (const bf16x8*)Bs;
        bf16x8 af[4], bfv[4];
#pragma unroll
        for (int i = 0; i < 4; i++) af[i] = Av[(wm + i * 16 + lm) * 4 + lq];
#pragma unroll
        for (int i = 0; i < 4; i++) bfv[i] = Bv[(wn + i * 16 + lm) * 4 + lq];
#pragma unroll
        for (int mi = 0; mi < 4; mi++)
#pragma unroll
            for (int ni = 0; ni < 4; ni++)
                acc[mi][ni] = __builtin_amdgcn_mfma_f32_16x16x32_bf16(af[mi], bfv[ni], acc[mi][ni], 0, 0, 0);
        __syncthreads();
    }
#pragma unroll
    for (int mi = 0; mi < 4; mi++) {
#pragma unroll
        for (int ni = 0; ni < 4; ni++) {
            int colg = nbase + wn + ni * 16 + lm;
            float bias = b1[e * H_ + colg];
#pragma unroll
            for (int r = 0; r < 4; r++) {
                int rowl = wm + mi * 16 + lq * 4 + r;
                float v = acc[mi][ni][r] + bias;
                v = v > 0.f ? v : 0.f;
                h[(size_t)(slot_base + rowl) * H_ + colg] = (bf16)v;
            }
        }
    }
}

// ---------------- GEMM2: y[row] += gate * (h @ W2[e] + b2[e]) ----------------
__global__ __launch_bounds__(256) void k_gemm2(
    const bf16* __restrict__ h, const bf16* __restrict__ w2t,
    const float* __restrict__ b2, const int* __restrict__ row_ids,
    const float* __restrict__ slot_gate, const int* __restrict__ tile_expert,
    float* __restrict__ y) {
    int e = tile_expert[blockIdx.x];
    if (e < 0) return;
    int slot_base = blockIdx.x * 128;
    int nbase = blockIdx.y * 128;
    __shared__ __align__(16) bf16 As[128 * 32];
    __shared__ __align__(16) bf16 Bs[128 * 32];
    int t = threadIdx.x;
    int m0 = t >> 2, kc = (t & 3) * 8;
    int m1 = m0 + 64;
    const bf16* ga0 = h + (size_t)(slot_base + m0) * H_ + kc;
    const bf16* ga1 = h + (size_t)(slot_base + m1) * H_ + kc;
    const bf16* gb0 = w2t + ((size_t)e * OUT_ + nbase + m0) * H_ + kc;
    const bf16* gb1 = w2t + ((size_t)e * OUT_ + nbase + m1) * H_ + kc;
    int w = t >> 6, lane = t & 63;
    int wm = (w >> 1) * 64, wn = (w & 1) * 64;
    int lm = lane & 15, lq = lane >> 4;
    f32x4 acc[4][4] = {};
    for (int k0 = 0; k0 < H_; k0 += 32) {
        async16(ga0 + k0, As + t * 8);
        async16(ga1 + k0, As + (t + 256) * 8);
        async16(gb0 + k0, Bs + t * 8);
        async16(gb1 + k0, Bs + (t + 256) * 8);
        __syncthreads();
        const bf16x8* Av = (const bf16x8*)As;
        const bf16x8* Bv = (const bf16x8*)Bs;
        bf16x8 af[4], bfv[4];
#pragma unroll
        for (int i = 0; i < 4; i++) af[i] = Av[(wm + i * 16 + lm) * 4 + lq];
#pragma unroll
        for (int i = 0; i < 4; i++) bfv[i] = Bv[(wn + i * 16 + lm) * 4 + lq];
#pragma unroll
        for (int mi = 0; mi < 4; mi++)
#pragma unroll
            for (int ni = 0; ni < 4; ni++)
                acc[mi][ni] = __builtin_amdgcn_mfma_f32_16x16x32_bf16(af[mi], bfv[ni], acc[mi][ni], 0, 0, 0);
        __syncthreads();
    }
#pragma unroll
    for (int mi = 0; mi < 4; mi++) {
#pragma unroll
        for (int ni = 0; ni < 4; ni++) {
            int colg = nbase + wn + ni * 16 + lm;
            float bias = b2[e * OUT_ + colg];
#pragma unroll
            for (int r = 0; r < 4; r++) {
                int rowl = wm + mi * 16 + lq * 4 + r;
                int slot = slot_base + rowl;
                int rid = row_ids[slot];
                if (rid >= 0) {
                    float g = slot_gate[slot];
                    atomicAdd(&y[(size_t)rid * OUT_ + colg], g * (acc[mi][ni][r] + bias));
                }
            }
        }
    }
}

// ---------------- loss: cv^2(importance) + cv^2(load), ddof=1 ----------------
__global__ void k_loss(const float* __restrict__ importance, const int* __restrict__ counts,
                       float* __restrict__ loss_out) {
    if (threadIdx.x == 0 && blockIdx.x == 0) {
        float si = 0.f, sl = 0.f;
        for (int e = 0; e < E_; e++) { si += importance[e]; sl += (float)counts[e]; }
        float mi_ = si / (float)E_, ml_ = sl / (float)E_;
        float vi = 0.f, vl = 0.f;
        for (int e = 0; e < E_; e++) {
            float d = importance[e] - mi_; vi += d * d;
            float d2 = (float)counts[e] - ml_; vl += d2 * d2;
        }
        vi /= (float)(E_ - 1); vl /= (float)(E_ - 1);
        *loss_out = vi / (mi_ * mi_ + 1e-10f) + vl / (ml_ * ml_ + 1e-10f);
    }
}

extern "C" void kernel_launch(void* const* d_in, const int* in_sizes, int n_in,
                              void* d_out, int out_size, void* d_ws, size_t ws_size,
                              hipStream_t stream) {
    (void)in_sizes; (void)n_in; (void)out_size; (void)ws_size;
    const float* x = (const float*)d_in[0];
    const float* wgate = (const float*)d_in[1];
    const float* W1 = (const float*)d_in[2];
    const float* b1 = (const float*)d_in[3];
    const float* W2 = (const float*)d_in[4];
    const float* b2 = (const float*)d_in[5];
    float* y = (float*)d_out;  // [B*OUT] floats, then loss scalar at [B*OUT]

    char* p = (char*)d_ws;
    auto alloc = [&](size_t bytes) {
        char* q = p;
        p += (bytes + 255) & ~(size_t)255;
        return q;
    };
    bf16* xbf = (bf16*)alloc((size_t)B_ * IN_ * 2);          // 16 MB
    bf16* w1t = (bf16*)alloc((size_t)E_ * H_ * IN_ * 2);     // 16 MB  [E][H][IN]
    bf16* w2t = (bf16*)alloc((size_t)E_ * OUT_ * H_ * 2);    // 4 MB   [E][OUT][H]
    bf16* h = (bf16*)alloc((size_t)MAXSLOTS * H_ * 2);       // 27 MB
    int* row_ids = (int*)alloc((size_t)MAXSLOTS * 4);
    float* slot_gate = (float*)alloc((size_t)MAXSLOTS * 4);
    int* top_idx = (int*)alloc((size_t)B_ * KTOP * 4);
    float* top_gate = (float*)alloc((size_t)B_ * KTOP * 4);
    int* counts = (int*)alloc(E_ * 4);
    int* fill = (int*)alloc(E_ * 4);
    int* offsets = (int*)alloc((E_ + 1) * 4);
    int* tile_expert = (int*)alloc(NTILES * 4);
    float* importance = (float*)alloc(E_ * 4);
    bf16* zero_row = (bf16*)alloc(IN_ * 2);

    k_init<<<dim3((B_ * OUT_) / 256), dim3(256), 0, stream>>>(
        y, row_ids, slot_gate, tile_expert, fill, importance, zero_row);
    k_transpose<<<dim3((IN_ / 64) * (H_ / 64), E_), dim3(256), 0, stream>>>(W1, w1t, IN_, H_);
    k_transpose<<<dim3((H_ / 64) * (OUT_ / 64), E_), dim3(256), 0, stream>>>(W2, w2t, H_, OUT_);
    k_gating<<<dim3(B_ / 4), dim3(256), 0, stream>>>(x, wgate, xbf, top_idx, top_gate);
    k_hist_scan<<<dim3(1), dim3(256), 0, stream>>>(top_idx, counts, offsets, tile_expert);
    k_scatter<<<dim3((B_ * KTOP) / 256), dim3(256), 0, stream>>>(
        top_idx, top_gate, offsets, fill, row_ids, slot_gate, importance);
    k_gemm1<<<dim3(NTILES, H_ / 128), dim3(256), 0, stream>>>(
        xbf, w1t, b1, row_ids, tile_expert, zero_row, h);
    k_gemm2<<<dim3(NTILES, OUT_ / 128), dim3(256), 0, stream>>>(
        h, w2t, b2, row_ids, slot_gate, tile_expert, y);
    k_loss<<<dim3(1), dim3(64), 0, stream>>>(importance, counts, y + (size_t)B_ * OUT_);
}

// Round 3
// 263.141 us; speedup vs baseline: 1.9976x; 1.2246x over previous
//
#include <hip/hip_runtime.h>

#define B_ 8192
#define IN_ 1024
#define OUT_ 256
#define E_ 16
#define KTOP 3
#define H_ 512
#define MAXSLOTS 26624   // 24576 + 16*127 rounded up to 128-multiple capacity
#define NTILES 208       // MAXSLOTS / 128

typedef __bf16 bf16;
typedef __bf16 bf16x4 __attribute__((ext_vector_type(4)));
typedef __bf16 bf16x8 __attribute__((ext_vector_type(8)));
typedef float f32x4 __attribute__((ext_vector_type(4)));

// async global->LDS, 16B per lane. LDS dest must be wave-uniform base + lane*16.
__device__ __forceinline__ void async16(const bf16* g, bf16* l) {
    __builtin_amdgcn_global_load_lds(
        (const __attribute__((address_space(1))) void*)g,
        (__attribute__((address_space(3))) void*)l,
        16, 0, 0);
}

// ---------------- init (y is fully written by k_combine; no y zeroing needed) ----------------
__global__ __launch_bounds__(256) void k_init(
    int* __restrict__ row_ids, int* __restrict__ tile_expert, int* __restrict__ fill,
    float* __restrict__ importance, bf16* __restrict__ zero_row) {
    int id = blockIdx.x * 256 + threadIdx.x;
    if (id < MAXSLOTS) row_ids[id] = -1;
    if (id < NTILES) tile_expert[id] = -1;
    if (id < E_) { fill[id] = 0; importance[id] = 0.f; }
    if (id < IN_) zero_row[id] = (bf16)0.f;
}

// ---------------- wgT[e][j] = wg[j][e]  (64 KB, one-shot) ----------------
__global__ __launch_bounds__(256) void k_wgt(
    const float* __restrict__ wg, float* __restrict__ wgT) {
    int id = blockIdx.x * 256 + threadIdx.x;  // 16384
    int e = id >> 10, j = id & 1023;
    wgT[id] = wg[j * E_ + e];
}

// ---------------- transpose+convert weights: in [E][K][N] f32 -> out [E][N][K] bf16 ----------------
__global__ __launch_bounds__(256) void k_transpose(
    const float* __restrict__ in, bf16* __restrict__ out, int Kd, int Nd) {
    __shared__ float tile[64][65];
    int e = blockIdx.y;
    int ntn = Nd >> 6;
    int tk = blockIdx.x / ntn, tn = blockIdx.x % ntn;
    int t = threadIdx.x;
    int r = t >> 6, c = t & 63;
    const float* src = in + ((size_t)e * Kd + tk * 64) * Nd + (size_t)tn * 64;
#pragma unroll
    for (int i = 0; i < 16; i++) {
        int rr = r + i * 4;
        tile[rr][c] = src[(size_t)rr * Nd + c];
    }
    __syncthreads();
    bf16* dst = out + ((size_t)e * Nd + tn * 64) * Kd + (size_t)tk * 64;
#pragma unroll
    for (int i = 0; i < 16; i++) {
        int rr = r + i * 4;
        dst[(size_t)rr * Kd + c] = (bf16)tile[c][rr];
    }
}

// ---------------- gating: coalesced wgT reads, top-3 softmax, emit x as bf16 ----------------
__global__ __launch_bounds__(256) void k_gating(
    const float* __restrict__ x, const float* __restrict__ wgT,
    bf16* __restrict__ xbf, int* __restrict__ top_idx, float* __restrict__ top_gate) {
    int t = threadIdx.x;
    int row = blockIdx.x * 4 + (t >> 6);
    int lane = t & 63;
    float acc[16];
#pragma unroll
    for (int e = 0; e < 16; e++) acc[e] = 0.f;
    const float4* x4p = (const float4*)(x + (size_t)row * IN_);
    const float4* w4 = (const float4*)wgT;  // [16][256] float4, coalesced per e
#pragma unroll
    for (int it = 0; it < 4; it++) {
        int j0 = it * 64 + lane;
        float4 xv = x4p[j0];
        bf16x4 xb;
        xb[0] = (bf16)xv.x; xb[1] = (bf16)xv.y; xb[2] = (bf16)xv.z; xb[3] = (bf16)xv.w;
        *(bf16x4*)(xbf + (size_t)row * IN_ + j0 * 4) = xb;
#pragma unroll
        for (int e = 0; e < 16; e++) {
            float4 wv = w4[e * 256 + j0];
            acc[e] += xv.x * wv.x + xv.y * wv.y + xv.z * wv.z + xv.w * wv.w;
        }
    }
#pragma unroll
    for (int e = 0; e < 16; e++) {
#pragma unroll
        for (int s = 32; s > 0; s >>= 1) acc[e] += __shfl_xor(acc[e], s, 64);
    }
    if (lane == 0) {
        float v[16];
#pragma unroll
        for (int e = 0; e < 16; e++) v[e] = acc[e];
        int idx[KTOP];
        float val[KTOP];
#pragma unroll
        for (int k = 0; k < KTOP; k++) {
            int best = 0;
            float bv = v[0];
            for (int e = 1; e < 16; e++) {
                if (v[e] > bv) { bv = v[e]; best = e; }
            }
            idx[k] = best; val[k] = bv; v[best] = -1e30f;
        }
        float e1 = __expf(val[1] - val[0]);
        float e2 = __expf(val[2] - val[0]);
        float inv = 1.f / (1.f + e1 + e2);
        float g[KTOP] = {inv, e1 * inv, e2 * inv};
#pragma unroll
        for (int k = 0; k < KTOP; k++) {
            top_idx[row * KTOP + k] = idx[k];
            top_gate[row * KTOP + k] = g[k];
        }
    }
}

// ---------------- hist + scan: ballot histogram (no atomics), offsets, tile map ----------------
__global__ __launch_bounds__(256) void k_hist_scan(
    const int* __restrict__ top_idx, int* __restrict__ counts,
    int* __restrict__ offsets, int* __restrict__ tile_expert) {
    __shared__ int wcnt[4][16];
    int t = threadIdx.x;
    int w = t >> 6, lane = t & 63;
    int cnt[16];
#pragma unroll
    for (int k = 0; k < 16; k++) cnt[k] = 0;
    for (int i = t; i < B_ * KTOP; i += 256) {
        int e = top_idx[i];
#pragma unroll
        for (int k = 0; k < 16; k++)
            cnt[k] += (int)__popcll(__ballot(e == k));
    }
    if (lane == 0) {
#pragma unroll
        for (int k = 0; k < 16; k++) wcnt[w][k] = cnt[k];
    }
    __syncthreads();
    if (t == 0) {
        int off = 0;
        for (int e = 0; e < E_; e++) {
            int c = wcnt[0][e] + wcnt[1][e] + wcnt[2][e] + wcnt[3][e];
            counts[e] = c;
            offsets[e] = off;
            int p = (c + 127) & ~127;
            int t0 = off >> 7, t1 = (off + p) >> 7;
            for (int tt = t0; tt < t1; ++tt) tile_expert[tt] = e;
            off += p;
        }
        offsets[E_] = off;
    }
}

// ---------------- scatter: assign slots, inverse map, accumulate importance ----------------
__global__ __launch_bounds__(256) void k_scatter(
    const int* __restrict__ top_idx, const float* __restrict__ top_gate,
    const int* __restrict__ offsets, int* __restrict__ fill,
    int* __restrict__ row_ids, int* __restrict__ rowslot,
    float* __restrict__ importance) {
    __shared__ int lcnt[16];
    __shared__ int lbase[16];
    __shared__ float limp[16];
    int t = threadIdx.x;
    if (t < 16) { lcnt[t] = 0; limp[t] = 0.f; }
    __syncthreads();
    int gid = blockIdx.x * 256 + t;  // [0, 24576) = b*KTOP + k
    int e = top_idx[gid];
    float g = top_gate[gid];
    int lpos = atomicAdd(&lcnt[e], 1);
    atomicAdd(&limp[e], g);
    __syncthreads();
    if (t < 16) {
        lbase[t] = (lcnt[t] > 0) ? atomicAdd(&fill[t], lcnt[t]) : 0;
        if (limp[t] != 0.f) atomicAdd(&importance[t], limp[t]);
    }
    __syncthreads();
    int slot = offsets[e] + lbase[e] + lpos;
    row_ids[slot] = gid / KTOP;
    rowslot[gid] = slot;
}

// ---------------- GEMM1: h = relu(gather(x) @ W1[e] + b1[e]) -> bf16 ----------------
__global__ __launch_bounds__(256) void k_gemm1(
    const bf16* __restrict__ xbf, const bf16* __restrict__ w1t,
    const float* __restrict__ b1, const int* __restrict__ row_ids,
    const int* __restrict__ tile_expert, const bf16* __restrict__ zero_row,
    bf16* __restrict__ h) {
    int e = tile_expert[blockIdx.x];
    if (e < 0) return;
    int slot_base = blockIdx.x * 128;
    int nbase = blockIdx.y * 128;
    __shared__ __align__(16) bf16 As[128 * 32];  // [m][k]
    __shared__ __align__(16) bf16 Bs[128 * 32];  // [n][k]
    int t = threadIdx.x;
    int m0 = t >> 2, kc = (t & 3) * 8;
    int m1 = m0 + 64;
    int r0 = row_ids[slot_base + m0];
    int r1 = row_ids[slot_base + m1];
    const bf16* ga0 = (r0 >= 0) ? xbf + (size_t)r0 * IN_ + kc : zero_row + kc;
    const bf16* ga1 = (r1 >= 0) ? xbf + (size_t)r1 * IN_ + kc : zero_row + kc;
    const bf16* gb0 = w1t + ((size_t)e * H_ + nbase + m0) * IN_ + kc;
    const bf16* gb1 = w1t + ((size_t)e * H_ + nbase + m1) * IN_ + kc;
    int w = t >> 6, lane = t & 63;
    int wm = (w >> 1) * 64, wn = (w & 1) * 64;
    int lm = lane & 15, lq = lane >> 4;
    f32x4 acc[4][4] = {};
    for (int k0 = 0; k0 < IN_; k0 += 32) {
        async16(ga0 + k0, As + t * 8);
        async16(ga1 + k0, As + (t + 256) * 8);
        async16(gb0 + k0, Bs + t * 8);
        async16(gb1 + k0, Bs + (t + 256) * 8);
        __syncthreads();
        const bf16x8* Av = (const bf16x8*)As;
        const bf16x8* Bv = (const bf16x8*)Bs;
        bf16x8 af[4], bfv[4];
#pragma unroll
        for (int i = 0; i < 4; i++) af[i] = Av[(wm + i * 16 + lm) * 4 + lq];
#pragma unroll
        for (int i = 0; i < 4; i++) bfv[i] = Bv[(wn + i * 16 + lm) * 4 + lq];
#pragma unroll
        for (int mi = 0; mi < 4; mi++)
#pragma unroll
            for (int ni = 0; ni < 4; ni++)
                acc[mi][ni] = __builtin_amdgcn_mfma_f32_16x16x32_bf16(af[mi], bfv[ni], acc[mi][ni], 0, 0, 0);
        __syncthreads();
    }
#pragma unroll
    for (int mi = 0; mi < 4; mi++) {
#pragma unroll
        for (int ni = 0; ni < 4; ni++) {
            int colg = nbase + wn + ni * 16 + lm;
            float bias = b1[e * H_ + colg];
#pragma unroll
            for (int r = 0; r < 4; r++) {
                int rowl = wm + mi * 16 + lq * 4 + r;
                float v = acc[mi][ni][r] + bias;
                v = v > 0.f ? v : 0.f;
                h[(size_t)(slot_base + rowl) * H_ + colg] = (bf16)v;
            }
        }
    }
}

// ---------------- GEMM2: eout[slot] = h[slot] @ W2[e] + b2[e]  (f32, no atomics) ----------------
__global__ __launch_bounds__(256) void k_gemm2(
    const bf16* __restrict__ h, const bf16* __restrict__ w2t,
    const float* __restrict__ b2, const int* __restrict__ tile_expert,
    float* __restrict__ eout) {
    int e = tile_expert[blockIdx.x];
    if (e < 0) return;
    int slot_base = blockIdx.x * 128;
    int nbase = blockIdx.y * 128;
    __shared__ __align__(16) bf16 As[128 * 32];
    __shared__ __align__(16) bf16 Bs[128 * 32];
    int t = threadIdx.x;
    int m0 = t >> 2, kc = (t & 3) * 8;
    int m1 = m0 + 64;
    const bf16* ga0 = h + (size_t)(slot_base + m0) * H_ + kc;
    const bf16* ga1 = h + (size_t)(slot_base + m1) * H_ + kc;
    const bf16* gb0 = w2t + ((size_t)e * OUT_ + nbase + m0) * H_ + kc;
    const bf16* gb1 = w2t + ((size_t)e * OUT_ + nbase + m1) * H_ + kc;
    int w = t >> 6, lane = t & 63;
    int wm = (w >> 1) * 64, wn = (w & 1) * 64;
    int lm = lane & 15, lq = lane >> 4;
    f32x4 acc[4][4] = {};
    for (int k0 = 0; k0 < H_; k0 += 32) {
        async16(ga0 + k0, As + t * 8);
        async16(ga1 + k0, As + (t + 256) * 8);
        async16(gb0 + k0, Bs + t * 8);
        async16(gb1 + k0, Bs + (t + 256) * 8);
        __syncthreads();
        const bf16x8* Av = (const bf16x8*)As;
        const bf16x8* Bv = (const bf16x8*)Bs;
        bf16x8 af[4], bfv[4];
#pragma unroll
        for (int i = 0; i < 4; i++) af[i] = Av[(wm + i * 16 + lm) * 4 + lq];
#pragma unroll
        for (int i = 0; i < 4; i++) bfv[i] = Bv[(wn + i * 16 + lm) * 4 + lq];
#pragma unroll
        for (int mi = 0; mi < 4; mi++)
#pragma unroll
            for (int ni = 0; ni < 4; ni++)
                acc[mi][ni] = __builtin_amdgcn_mfma_f32_16x16x32_bf16(af[mi], bfv[ni], acc[mi][ni], 0, 0, 0);
        __syncthreads();
    }
#pragma unroll
    for (int mi = 0; mi < 4; mi++) {
#pragma unroll
        for (int ni = 0; ni < 4; ni++) {
            int colg = nbase + wn + ni * 16 + lm;
            float bias = b2[e * OUT_ + colg];
#pragma unroll
            for (int r = 0; r < 4; r++) {
                int rowl = wm + mi * 16 + lq * 4 + r;
                eout[(size_t)(slot_base + rowl) * OUT_ + colg] = acc[mi][ni][r] + bias;
            }
        }
    }
}

// ---------------- combine: y[b] = sum_k gate_k * eout[slot_k]  (coalesced, no atomics) ----------------
__global__ __launch_bounds__(256) void k_combine(
    const float* __restrict__ eout, const int* __restrict__ rowslot,
    const float* __restrict__ top_gate, float* __restrict__ y) {
    int t = threadIdx.x;
    int b = blockIdx.x * 4 + (t >> 6);
    int lane = t & 63;
    int s0 = rowslot[b * 3], s1 = rowslot[b * 3 + 1], s2 = rowslot[b * 3 + 2];
    float g0 = top_gate[b * 3], g1 = top_gate[b * 3 + 1], g2 = top_gate[b * 3 + 2];
    const float4* e4 = (const float4*)eout;
    float4 v0 = e4[(size_t)s0 * 64 + lane];
    float4 v1 = e4[(size_t)s1 * 64 + lane];
    float4 v2 = e4[(size_t)s2 * 64 + lane];
    float4 r;
    r.x = g0 * v0.x + g1 * v1.x + g2 * v2.x;
    r.y = g0 * v0.y + g1 * v1.y + g2 * v2.y;
    r.z = g0 * v0.z + g1 * v1.z + g2 * v2.z;
    r.w = g0 * v0.w + g1 * v1.w + g2 * v2.w;
    ((float4*)y)[(size_t)b * 64 + lane] = r;
}

// ---------------- loss: cv^2(importance) + cv^2(load), ddof=1 ----------------
__global__ void k_loss(const float* __restrict__ importance, const int* __restrict__ counts,
                       float* __restrict__ loss_out) {
    if (threadIdx.x == 0 && blockIdx.x == 0) {
        float si = 0.f, sl = 0.f;
        for (int e = 0; e < E_; e++) { si += importance[e]; sl += (float)counts[e]; }
        float mi_ = si / (float)E_, ml_ = sl / (float)E_;
        float vi = 0.f, vl = 0.f;
        for (int e = 0; e < E_; e++) {
            float d = importance[e] - mi_; vi += d * d;
            float d2 = (float)counts[e] - ml_; vl += d2 * d2;
        }
        vi /= (float)(E_ - 1); vl /= (float)(E_ - 1);
        *loss_out = vi / (mi_ * mi_ + 1e-10f) + vl / (ml_ * ml_ + 1e-10f);
    }
}

extern "C" void kernel_launch(void* const* d_in, const int* in_sizes, int n_in,
                              void* d_out, int out_size, void* d_ws, size_t ws_size,
                              hipStream_t stream) {
    (void)in_sizes; (void)n_in; (void)out_size; (void)ws_size;
    const float* x = (const float*)d_in[0];
    const float* wgate = (const float*)d_in[1];
    const float* W1 = (const float*)d_in[2];
    const float* b1 = (const float*)d_in[3];
    const float* W2 = (const float*)d_in[4];
    const float* b2 = (const float*)d_in[5];
    float* y = (float*)d_out;  // [B*OUT] floats, then loss scalar at [B*OUT]

    char* p = (char*)d_ws;
    auto alloc = [&](size_t bytes) {
        char* q = p;
        p += (bytes + 255) & ~(size_t)255;
        return q;
    };
    bf16* xbf = (bf16*)alloc((size_t)B_ * IN_ * 2);          // 16 MB (dead after gemm1)
    bf16* w1t = (bf16*)alloc((size_t)E_ * H_ * IN_ * 2);     // 16 MB (dead after gemm1)
    bf16* w2t = (bf16*)alloc((size_t)E_ * OUT_ * H_ * 2);    // 4 MB
    bf16* h = (bf16*)alloc((size_t)MAXSLOTS * H_ * 2);       // 27 MB
    int* row_ids = (int*)alloc((size_t)MAXSLOTS * 4);
    int* rowslot = (int*)alloc((size_t)B_ * KTOP * 4);
    int* top_idx = (int*)alloc((size_t)B_ * KTOP * 4);
    float* top_gate = (float*)alloc((size_t)B_ * KTOP * 4);
    int* counts = (int*)alloc(E_ * 4);
    int* fill = (int*)alloc(E_ * 4);
    int* offsets = (int*)alloc((E_ + 1) * 4);
    int* tile_expert = (int*)alloc(NTILES * 4);
    float* importance = (float*)alloc(E_ * 4);
    bf16* zero_row = (bf16*)alloc(IN_ * 2);
    float* wgT = (float*)alloc((size_t)E_ * IN_ * 4);        // 64 KB
    // eout (27 MB f32) aliases xbf+w1t (32 MB): xbf/w1t are dead once gemm1
    // completes, and gemm2/combine run strictly after gemm1 on the same stream.
    float* eout = (float*)xbf;

    k_init<<<dim3((MAXSLOTS + 255) / 256), dim3(256), 0, stream>>>(
        row_ids, tile_expert, fill, importance, zero_row);
    k_wgt<<<dim3((E_ * IN_) / 256), dim3(256), 0, stream>>>(wgate, wgT);
    k_transpose<<<dim3((IN_ / 64) * (H_ / 64), E_), dim3(256), 0, stream>>>(W1, w1t, IN_, H_);
    k_transpose<<<dim3((H_ / 64) * (OUT_ / 64), E_), dim3(256), 0, stream>>>(W2, w2t, H_, OUT_);
    k_gating<<<dim3(B_ / 4), dim3(256), 0, stream>>>(x, wgT, xbf, top_idx, top_gate);
    k_hist_scan<<<dim3(1), dim3(256), 0, stream>>>(top_idx, counts, offsets, tile_expert);
    k_scatter<<<dim3((B_ * KTOP) / 256), dim3(256), 0, stream>>>(
        top_idx, top_gate, offsets, fill, row_ids, rowslot, importance);
    k_gemm1<<<dim3(NTILES, H_ / 128), dim3(256), 0, stream>>>(
        xbf, w1t, b1, row_ids, tile_expert, zero_row, h);
    k_gemm2<<<dim3(NTILES, OUT_ / 128), dim3(256), 0, stream>>>(
        h, w2t, b2, tile_expert, eout);
    k_combine<<<dim3(B_ / 4), dim3(256), 0, stream>>>(eout, rowslot, top_gate, y);
    k_loss<<<dim3(1), dim3(64), 0, stream>>>(importance, counts, y + (size_t)B_ * OUT_);
}

// Round 4
// 250.228 us; speedup vs baseline: 2.1007x; 1.0516x over previous
//
#include <hip/hip_runtime.h>

#define B_ 8192
#define IN_ 1024
#define OUT_ 256
#define E_ 16
#define KTOP 3
#define H_ 512
#define MAXSLOTS 26624   // 24576 + 16*127 rounded up to 128-multiple capacity
#define NTILES 208       // MAXSLOTS / 128

typedef __bf16 bf16;
typedef __bf16 bf16x4 __attribute__((ext_vector_type(4)));
typedef __bf16 bf16x8 __attribute__((ext_vector_type(8)));
typedef float f32x4 __attribute__((ext_vector_type(4)));

// async global->LDS, 16B per lane. LDS dest must be wave-uniform base + lane*16.
__device__ __forceinline__ void async16(const bf16* g, bf16* l) {
    __builtin_amdgcn_global_load_lds(
        (const __attribute__((address_space(1))) void*)g,
        (__attribute__((address_space(3))) void*)l,
        16, 0, 0);
}

// ---------------- init + wgT (fused) ----------------
__global__ __launch_bounds__(256) void k_init(
    int* __restrict__ row_ids, int* __restrict__ tile_expert, int* __restrict__ fill,
    float* __restrict__ importance, bf16* __restrict__ zero_row,
    const float* __restrict__ wg, float* __restrict__ wgT) {
    int id = blockIdx.x * 256 + threadIdx.x;
    if (id < MAXSLOTS) row_ids[id] = -1;
    if (id < NTILES) tile_expert[id] = -1;
    if (id < E_) { fill[id] = 0; importance[id] = 0.f; }
    if (id < IN_) zero_row[id] = (bf16)0.f;
    if (id < E_ * IN_) {  // wgT[e][j] = wg[j][e]
        int e = id >> 10, j = id & 1023;
        wgT[id] = wg[j * E_ + e];
    }
}

// ---------------- fused transpose+convert: W1 and W2 in one launch ----------------
// in [E][K][N] f32 -> out [E][N][K] bf16
__global__ __launch_bounds__(256) void k_transpose(
    const float* __restrict__ W1, bf16* __restrict__ w1t,
    const float* __restrict__ W2, bf16* __restrict__ w2t) {
    __shared__ float tile[64][65];
    int bx = blockIdx.x;
    const float* in; bf16* out; int Kd, Nd, e, tk, tn;
    if (bx < 2048) {            // W1: 16 experts x (16 x 8) tiles
        in = W1; out = w1t; Kd = IN_; Nd = H_;
        e = bx >> 7; int tt = bx & 127; tk = tt >> 3; tn = tt & 7;
    } else {                    // W2: 16 experts x (8 x 4) tiles
        bx -= 2048;
        in = W2; out = w2t; Kd = H_; Nd = OUT_;
        e = bx >> 5; int tt = bx & 31; tk = tt >> 2; tn = tt & 3;
    }
    int t = threadIdx.x;
    int r = t >> 6, c = t & 63;
    const float* src = in + ((size_t)e * Kd + tk * 64) * Nd + (size_t)tn * 64;
#pragma unroll
    for (int i = 0; i < 16; i++) {
        int rr = r + i * 4;
        tile[rr][c] = src[(size_t)rr * Nd + c];
    }
    __syncthreads();
    bf16* dst = out + ((size_t)e * Nd + tn * 64) * Kd + (size_t)tk * 64;
#pragma unroll
    for (int i = 0; i < 16; i++) {
        int rr = r + i * 4;
        dst[(size_t)rr * Kd + c] = (bf16)tile[c][rr];
    }
}

// ---------------- gating: coalesced wgT reads, top-3 softmax, emit x as bf16 ----------------
__global__ __launch_bounds__(256) void k_gating(
    const float* __restrict__ x, const float* __restrict__ wgT,
    bf16* __restrict__ xbf, int* __restrict__ top_idx, float* __restrict__ top_gate) {
    int t = threadIdx.x;
    int row = blockIdx.x * 4 + (t >> 6);
    int lane = t & 63;
    float acc[16];
#pragma unroll
    for (int e = 0; e < 16; e++) acc[e] = 0.f;
    const float4* x4p = (const float4*)(x + (size_t)row * IN_);
    const float4* w4 = (const float4*)wgT;  // [16][256] float4, coalesced per e
#pragma unroll
    for (int it = 0; it < 4; it++) {
        int j0 = it * 64 + lane;
        float4 xv = x4p[j0];
        bf16x4 xb;
        xb[0] = (bf16)xv.x; xb[1] = (bf16)xv.y; xb[2] = (bf16)xv.z; xb[3] = (bf16)xv.w;
        *(bf16x4*)(xbf + (size_t)row * IN_ + j0 * 4) = xb;
#pragma unroll
        for (int e = 0; e < 16; e++) {
            float4 wv = w4[e * 256 + j0];
            acc[e] += xv.x * wv.x + xv.y * wv.y + xv.z * wv.z + xv.w * wv.w;
        }
    }
#pragma unroll
    for (int e = 0; e < 16; e++) {
#pragma unroll
        for (int s = 32; s > 0; s >>= 1) acc[e] += __shfl_xor(acc[e], s, 64);
    }
    if (lane == 0) {
        float v[16];
#pragma unroll
        for (int e = 0; e < 16; e++) v[e] = acc[e];
        int idx[KTOP];
        float val[KTOP];
#pragma unroll
        for (int k = 0; k < KTOP; k++) {
            int best = 0;
            float bv = v[0];
            for (int e = 1; e < 16; e++) {
                if (v[e] > bv) { bv = v[e]; best = e; }
            }
            idx[k] = best; val[k] = bv; v[best] = -1e30f;
        }
        float e1 = __expf(val[1] - val[0]);
        float e2 = __expf(val[2] - val[0]);
        float inv = 1.f / (1.f + e1 + e2);
        float g[KTOP] = {inv, e1 * inv, e2 * inv};
#pragma unroll
        for (int k = 0; k < KTOP; k++) {
            top_idx[row * KTOP + k] = idx[k];
            top_gate[row * KTOP + k] = g[k];
        }
    }
}

// ---------------- hist + scan: ballot histogram (no atomics), offsets, tile map ----------------
__global__ __launch_bounds__(256) void k_hist_scan(
    const int* __restrict__ top_idx, int* __restrict__ counts,
    int* __restrict__ offsets, int* __restrict__ tile_expert) {
    __shared__ int wcnt[4][16];
    int t = threadIdx.x;
    int w = t >> 6, lane = t & 63;
    int cnt[16];
#pragma unroll
    for (int k = 0; k < 16; k++) cnt[k] = 0;
    for (int i = t; i < B_ * KTOP; i += 256) {
        int e = top_idx[i];
#pragma unroll
        for (int k = 0; k < 16; k++)
            cnt[k] += (int)__popcll(__ballot(e == k));
    }
    if (lane == 0) {
#pragma unroll
        for (int k = 0; k < 16; k++) wcnt[w][k] = cnt[k];
    }
    __syncthreads();
    if (t == 0) {
        int off = 0;
        for (int e = 0; e < E_; e++) {
            int c = wcnt[0][e] + wcnt[1][e] + wcnt[2][e] + wcnt[3][e];
            counts[e] = c;
            offsets[e] = off;
            int p = (c + 127) & ~127;
            int t0 = off >> 7, t1 = (off + p) >> 7;
            for (int tt = t0; tt < t1; ++tt) tile_expert[tt] = e;
            off += p;
        }
        offsets[E_] = off;
    }
}

// ---------------- scatter: assign slots, inverse map, accumulate importance ----------------
__global__ __launch_bounds__(256) void k_scatter(
    const int* __restrict__ top_idx, const float* __restrict__ top_gate,
    const int* __restrict__ offsets, int* __restrict__ fill,
    int* __restrict__ row_ids, int* __restrict__ rowslot,
    float* __restrict__ importance) {
    __shared__ int lcnt[16];
    __shared__ int lbase[16];
    __shared__ float limp[16];
    int t = threadIdx.x;
    if (t < 16) { lcnt[t] = 0; limp[t] = 0.f; }
    __syncthreads();
    int gid = blockIdx.x * 256 + t;  // [0, 24576) = b*KTOP + k
    int e = top_idx[gid];
    float g = top_gate[gid];
    int lpos = atomicAdd(&lcnt[e], 1);
    atomicAdd(&limp[e], g);
    __syncthreads();
    if (t < 16) {
        lbase[t] = (lcnt[t] > 0) ? atomicAdd(&fill[t], lcnt[t]) : 0;
        if (limp[t] != 0.f) atomicAdd(&importance[t], limp[t]);
    }
    __syncthreads();
    int slot = offsets[e] + lbase[e] + lpos;
    row_ids[slot] = gid / KTOP;
    rowslot[gid] = slot;
}

// ======================= GEMMs: BK=128, XOR-swizzled LDS =======================
// LDS tile: rows x 128k as bf16 -> 16 chunks of 16B per row.
// Chunk at LDS position (row, cpos) holds global k-chunk (cpos&8)|((cpos&7)^(row&7)).
// Staging stays lane-contiguous (global_load_lds constraint); reads are 2-way max.

// ---------------- GEMM1: h = relu(gather(x) @ W1[e] + b1[e]) -> bf16 ----------------
__global__ __launch_bounds__(256, 2) void k_gemm1(
    const bf16* __restrict__ xbf, const bf16* __restrict__ w1t,
    const float* __restrict__ b1, const int* __restrict__ row_ids,
    const int* __restrict__ tile_expert, const bf16* __restrict__ zero_row,
    bf16* __restrict__ h) {
    int e = tile_expert[blockIdx.x];
    if (e < 0) return;
    int slot_base = blockIdx.x * 128;
    int nbase = blockIdx.y * 128;
    __shared__ __align__(16) bf16 As[128 * 128];  // 32 KB
    __shared__ __align__(16) bf16 Bs[128 * 128];  // 32 KB
    int t = threadIdx.x;
    // staging: 8 A-chunks + 8 B-chunks per thread per iter
    int rmod = (t >> 4) & 7;
    int cpos = t & 15;
    int cglob = (cpos & 8) | ((cpos & 7) ^ rmod);
    const bf16* gA[8];
    const bf16* gB[8];
#pragma unroll
    for (int j = 0; j < 8; j++) {
        int m = j * 16 + (t >> 4);
        int rid = row_ids[slot_base + m];
        gA[j] = ((rid >= 0) ? xbf + (size_t)rid * IN_ : zero_row) + cglob * 8;
        gB[j] = w1t + ((size_t)e * H_ + nbase + m) * IN_ + cglob * 8;
    }
    int w = t >> 6, lane = t & 63;
    int wm = (w >> 1) * 64, wn = (w & 1) * 64;
    int lm = lane & 15, lq = lane >> 4;
    f32x4 acc[4][4] = {};
    for (int k0 = 0; k0 < IN_; k0 += 128) {
#pragma unroll
        for (int j = 0; j < 8; j++) {
            async16(gA[j] + k0, As + (j * 256 + t) * 8);
            async16(gB[j] + k0, Bs + (j * 256 + t) * 8);
        }
        __syncthreads();
        const bf16x8* Av = (const bf16x8*)As;
        const bf16x8* Bv = (const bf16x8*)Bs;
#pragma unroll
        for (int ks = 0; ks < 4; ks++) {
            int kc = ks * 4 + lq;
            bf16x8 af[4], bfv[4];
#pragma unroll
            for (int i = 0; i < 4; i++) {
                int row = wm + i * 16 + lm;
                af[i] = Av[row * 16 + ((kc & 8) | ((kc & 7) ^ (row & 7)))];
            }
#pragma unroll
            for (int i = 0; i < 4; i++) {
                int row = wn + i * 16 + lm;
                bfv[i] = Bv[row * 16 + ((kc & 8) | ((kc & 7) ^ (row & 7)))];
            }
#pragma unroll
            for (int mi = 0; mi < 4; mi++)
#pragma unroll
                for (int ni = 0; ni < 4; ni++)
                    acc[mi][ni] = __builtin_amdgcn_mfma_f32_16x16x32_bf16(af[mi], bfv[ni], acc[mi][ni], 0, 0, 0);
        }
        __syncthreads();
    }
#pragma unroll
    for (int mi = 0; mi < 4; mi++) {
#pragma unroll
        for (int ni = 0; ni < 4; ni++) {
            int colg = nbase + wn + ni * 16 + lm;
            float bias = b1[e * H_ + colg];
#pragma unroll
            for (int r = 0; r < 4; r++) {
                int rowl = wm + mi * 16 + lq * 4 + r;
                float v = acc[mi][ni][r] + bias;
                v = v > 0.f ? v : 0.f;
                h[(size_t)(slot_base + rowl) * H_ + colg] = (bf16)v;
            }
        }
    }
}

// ---------------- GEMM2: eout[slot] = h[slot] @ W2[e] + b2[e]  (f32, no atomics) ----------------
__global__ __launch_bounds__(256, 2) void k_gemm2(
    const bf16* __restrict__ h, const bf16* __restrict__ w2t,
    const float* __restrict__ b2, const int* __restrict__ tile_expert,
    float* __restrict__ eout) {
    int e = tile_expert[blockIdx.x];
    if (e < 0) return;
    int slot_base = blockIdx.x * 128;
    int nbase = blockIdx.y * 128;
    __shared__ __align__(16) bf16 As[128 * 128];
    __shared__ __align__(16) bf16 Bs[128 * 128];
    int t = threadIdx.x;
    int rmod = (t >> 4) & 7;
    int cpos = t & 15;
    int cglob = (cpos & 8) | ((cpos & 7) ^ rmod);
    const bf16* gA[8];
    const bf16* gB[8];
#pragma unroll
    for (int j = 0; j < 8; j++) {
        int m = j * 16 + (t >> 4);
        gA[j] = h + (size_t)(slot_base + m) * H_ + cglob * 8;
        gB[j] = w2t + ((size_t)e * OUT_ + nbase + m) * H_ + cglob * 8;
    }
    int w = t >> 6, lane = t & 63;
    int wm = (w >> 1) * 64, wn = (w & 1) * 64;
    int lm = lane & 15, lq = lane >> 4;
    f32x4 acc[4][4] = {};
    for (int k0 = 0; k0 < H_; k0 += 128) {
#pragma unroll
        for (int j = 0; j < 8; j++) {
            async16(gA[j] + k0, As + (j * 256 + t) * 8);
            async16(gB[j] + k0, Bs + (j * 256 + t) * 8);
        }
        __syncthreads();
        const bf16x8* Av = (const bf16x8*)As;
        const bf16x8* Bv = (const bf16x8*)Bs;
#pragma unroll
        for (int ks = 0; ks < 4; ks++) {
            int kc = ks * 4 + lq;
            bf16x8 af[4], bfv[4];
#pragma unroll
            for (int i = 0; i < 4; i++) {
                int row = wm + i * 16 + lm;
                af[i] = Av[row * 16 + ((kc & 8) | ((kc & 7) ^ (row & 7)))];
            }
#pragma unroll
            for (int i = 0; i < 4; i++) {
                int row = wn + i * 16 + lm;
                bfv[i] = Bv[row * 16 + ((kc & 8) | ((kc & 7) ^ (row & 7)))];
            }
#pragma unroll
            for (int mi = 0; mi < 4; mi++)
#pragma unroll
                for (int ni = 0; ni < 4; ni++)
                    acc[mi][ni] = __builtin_amdgcn_mfma_f32_16x16x32_bf16(af[mi], bfv[ni], acc[mi][ni], 0, 0, 0);
        }
        __syncthreads();
    }
#pragma unroll
    for (int mi = 0; mi < 4; mi++) {
#pragma unroll
        for (int ni = 0; ni < 4; ni++) {
            int colg = nbase + wn + ni * 16 + lm;
            float bias = b2[e * OUT_ + colg];
#pragma unroll
            for (int r = 0; r < 4; r++) {
                int rowl = wm + mi * 16 + lq * 4 + r;
                eout[(size_t)(slot_base + rowl) * OUT_ + colg] = acc[mi][ni][r] + bias;
            }
        }
    }
}

// ---------------- combine: y[b] = sum_k gate_k * eout[slot_k]  (coalesced, no atomics) ----------------
__global__ __launch_bounds__(256) void k_combine(
    const float* __restrict__ eout, const int* __restrict__ rowslot,
    const float* __restrict__ top_gate, float* __restrict__ y) {
    int t = threadIdx.x;
    int b = blockIdx.x * 4 + (t >> 6);
    int lane = t & 63;
    int s0 = rowslot[b * 3], s1 = rowslot[b * 3 + 1], s2 = rowslot[b * 3 + 2];
    float g0 = top_gate[b * 3], g1 = top_gate[b * 3 + 1], g2 = top_gate[b * 3 + 2];
    const float4* e4 = (const float4*)eout;
    float4 v0 = e4[(size_t)s0 * 64 + lane];
    float4 v1 = e4[(size_t)s1 * 64 + lane];
    float4 v2 = e4[(size_t)s2 * 64 + lane];
    float4 r;
    r.x = g0 * v0.x + g1 * v1.x + g2 * v2.x;
    r.y = g0 * v0.y + g1 * v1.y + g2 * v2.y;
    r.z = g0 * v0.z + g1 * v1.z + g2 * v2.z;
    r.w = g0 * v0.w + g1 * v1.w + g2 * v2.w;
    ((float4*)y)[(size_t)b * 64 + lane] = r;
}

// ---------------- loss: cv^2(importance) + cv^2(load), ddof=1 ----------------
__global__ void k_loss(const float* __restrict__ importance, const int* __restrict__ counts,
                       float* __restrict__ loss_out) {
    if (threadIdx.x == 0 && blockIdx.x == 0) {
        float si = 0.f, sl = 0.f;
        for (int e = 0; e < E_; e++) { si += importance[e]; sl += (float)counts[e]; }
        float mi_ = si / (float)E_, ml_ = sl / (float)E_;
        float vi = 0.f, vl = 0.f;
        for (int e = 0; e < E_; e++) {
            float d = importance[e] - mi_; vi += d * d;
            float d2 = (float)counts[e] - ml_; vl += d2 * d2;
        }
        vi /= (float)(E_ - 1); vl /= (float)(E_ - 1);
        *loss_out = vi / (mi_ * mi_ + 1e-10f) + vl / (ml_ * ml_ + 1e-10f);
    }
}

extern "C" void kernel_launch(void* const* d_in, const int* in_sizes, int n_in,
                              void* d_out, int out_size, void* d_ws, size_t ws_size,
                              hipStream_t stream) {
    (void)in_sizes; (void)n_in; (void)out_size; (void)ws_size;
    const float* x = (const float*)d_in[0];
    const float* wgate = (const float*)d_in[1];
    const float* W1 = (const float*)d_in[2];
    const float* b1 = (const float*)d_in[3];
    const float* W2 = (const float*)d_in[4];
    const float* b2 = (const float*)d_in[5];
    float* y = (float*)d_out;  // [B*OUT] floats, then loss scalar at [B*OUT]

    char* p = (char*)d_ws;
    auto alloc = [&](size_t bytes) {
        char* q = p;
        p += (bytes + 255) & ~(size_t)255;
        return q;
    };
    bf16* xbf = (bf16*)alloc((size_t)B_ * IN_ * 2);          // 16 MB (dead after gemm1)
    bf16* w1t = (bf16*)alloc((size_t)E_ * H_ * IN_ * 2);     // 16 MB (dead after gemm1)
    bf16* w2t = (bf16*)alloc((size_t)E_ * OUT_ * H_ * 2);    // 4 MB
    bf16* h = (bf16*)alloc((size_t)MAXSLOTS * H_ * 2);       // 27 MB
    int* row_ids = (int*)alloc((size_t)MAXSLOTS * 4);
    int* rowslot = (int*)alloc((size_t)B_ * KTOP * 4);
    int* top_idx = (int*)alloc((size_t)B_ * KTOP * 4);
    float* top_gate = (float*)alloc((size_t)B_ * KTOP * 4);
    int* counts = (int*)alloc(E_ * 4);
    int* fill = (int*)alloc(E_ * 4);
    int* offsets = (int*)alloc((E_ + 1) * 4);
    int* tile_expert = (int*)alloc(NTILES * 4);
    float* importance = (float*)alloc(E_ * 4);
    bf16* zero_row = (bf16*)alloc(IN_ * 2);
    float* wgT = (float*)alloc((size_t)E_ * IN_ * 4);        // 64 KB
    // eout (27 MB f32) aliases xbf+w1t (32 MB): xbf/w1t are dead once gemm1
    // completes, and gemm2/combine run strictly after gemm1 on the same stream.
    float* eout = (float*)xbf;

    k_init<<<dim3((MAXSLOTS + 255) / 256), dim3(256), 0, stream>>>(
        row_ids, tile_expert, fill, importance, zero_row, wgate, wgT);
    k_transpose<<<dim3(2048 + 512), dim3(256), 0, stream>>>(W1, w1t, W2, w2t);
    k_gating<<<dim3(B_ / 4), dim3(256), 0, stream>>>(x, wgT, xbf, top_idx, top_gate);
    k_hist_scan<<<dim3(1), dim3(256), 0, stream>>>(top_idx, counts, offsets, tile_expert);
    k_scatter<<<dim3((B_ * KTOP) / 256), dim3(256), 0, stream>>>(
        top_idx, top_gate, offsets, fill, row_ids, rowslot, importance);
    k_gemm1<<<dim3(NTILES, H_ / 128), dim3(256), 0, stream>>>(
        xbf, w1t, b1, row_ids, tile_expert, zero_row, h);
    k_gemm2<<<dim3(NTILES, OUT_ / 128), dim3(256), 0, stream>>>(
        h, w2t, b2, tile_expert, eout);
    k_combine<<<dim3(B_ / 4), dim3(256), 0, stream>>>(eout, rowslot, top_gate, y);
    k_loss<<<dim3(1), dim3(64), 0, stream>>>(importance, counts, y + (size_t)B_ * OUT_);
}

// Round 5
// 221.277 us; speedup vs baseline: 2.3756x; 1.1308x over previous
//
#include <hip/hip_runtime.h>

#define B_ 8192
#define IN_ 1024
#define OUT_ 256
#define E_ 16
#define KTOP 3
#define H_ 512
#define MAXSLOTS 26624   // 24576 + 16*127 rounded up
#define NTILES 208       // MAXSLOTS / 128
#define HBLK 16          // hist/scatter blocks

typedef __bf16 bf16;
typedef __bf16 bf16x4 __attribute__((ext_vector_type(4)));
typedef __bf16 bf16x8 __attribute__((ext_vector_type(8)));
typedef float f32x4 __attribute__((ext_vector_type(4)));

// async global->LDS, 16B per lane. LDS dest must be wave-uniform base + lane*16.
__device__ __forceinline__ void async16(const bf16* g, bf16* l) {
    __builtin_amdgcn_global_load_lds(
        (const __attribute__((address_space(1))) void*)g,
        (__attribute__((address_space(3))) void*)l,
        16, 0, 0);
}

// ---------------- init + wgT (fused) ----------------
__global__ __launch_bounds__(256) void k_init(
    int* __restrict__ row_ids, int* __restrict__ tile_expert,
    bf16* __restrict__ zero_row,
    const float* __restrict__ wg, float* __restrict__ wgT) {
    int id = blockIdx.x * 256 + threadIdx.x;
    if (id < MAXSLOTS) row_ids[id] = -1;
    if (id < NTILES) tile_expert[id] = -1;
    if (id < IN_) zero_row[id] = (bf16)0.f;
    if (id < E_ * IN_) {  // wgT[e][j] = wg[j][e]
        int e = id >> 10, j = id & 1023;
        wgT[id] = wg[j * E_ + e];
    }
}

// ---------------- fused transpose+convert: W1 and W2 -> [E][N][K] bf16 ----------------
__global__ __launch_bounds__(256) void k_transpose(
    const float* __restrict__ W1, bf16* __restrict__ w1t,
    const float* __restrict__ W2, bf16* __restrict__ w2t) {
    __shared__ float tile[64][65];
    int bx = blockIdx.x;
    const float* in; bf16* out; int Kd, Nd, e, tk, tn;
    if (bx < 2048) {            // W1: 16 experts x (16 x 8) tiles
        in = W1; out = w1t; Kd = IN_; Nd = H_;
        e = bx >> 7; int tt = bx & 127; tk = tt >> 3; tn = tt & 7;
    } else {                    // W2: 16 experts x (8 x 4) tiles
        bx -= 2048;
        in = W2; out = w2t; Kd = H_; Nd = OUT_;
        e = bx >> 5; int tt = bx & 31; tk = tt >> 2; tn = tt & 3;
    }
    int t = threadIdx.x;
    int r = t >> 6, c = t & 63;
    const float* src = in + ((size_t)e * Kd + tk * 64) * Nd + (size_t)tn * 64;
#pragma unroll
    for (int i = 0; i < 16; i++) {
        int rr = r + i * 4;
        tile[rr][c] = src[(size_t)rr * Nd + c];
    }
    __syncthreads();
    bf16* dst = out + ((size_t)e * Nd + tn * 64) * Kd + (size_t)tk * 64;
#pragma unroll
    for (int i = 0; i < 16; i++) {
        int rr = r + i * 4;
        dst[(size_t)rr * Kd + c] = (bf16)tile[c][rr];
    }
}

// ---------------- gating: coalesced wgT reads, top-3 softmax, emit x as bf16 ----------------
__global__ __launch_bounds__(256) void k_gating(
    const float* __restrict__ x, const float* __restrict__ wgT,
    bf16* __restrict__ xbf, int* __restrict__ top_idx, float* __restrict__ top_gate) {
    int t = threadIdx.x;
    int row = blockIdx.x * 4 + (t >> 6);
    int lane = t & 63;
    float acc[16];
#pragma unroll
    for (int e = 0; e < 16; e++) acc[e] = 0.f;
    const float4* x4p = (const float4*)(x + (size_t)row * IN_);
    const float4* w4 = (const float4*)wgT;
#pragma unroll
    for (int it = 0; it < 4; it++) {
        int j0 = it * 64 + lane;
        float4 xv = x4p[j0];
        bf16x4 xb;
        xb[0] = (bf16)xv.x; xb[1] = (bf16)xv.y; xb[2] = (bf16)xv.z; xb[3] = (bf16)xv.w;
        *(bf16x4*)(xbf + (size_t)row * IN_ + j0 * 4) = xb;
#pragma unroll
        for (int e = 0; e < 16; e++) {
            float4 wv = w4[e * 256 + j0];
            acc[e] += xv.x * wv.x + xv.y * wv.y + xv.z * wv.z + xv.w * wv.w;
        }
    }
#pragma unroll
    for (int e = 0; e < 16; e++) {
#pragma unroll
        for (int s = 32; s > 0; s >>= 1) acc[e] += __shfl_xor(acc[e], s, 64);
    }
    if (lane == 0) {
        float v[16];
#pragma unroll
        for (int e = 0; e < 16; e++) v[e] = acc[e];
        int idx[KTOP];
        float val[KTOP];
#pragma unroll
        for (int k = 0; k < KTOP; k++) {
            int best = 0;
            float bv = v[0];
            for (int e = 1; e < 16; e++) {
                if (v[e] > bv) { bv = v[e]; best = e; }
            }
            idx[k] = best; val[k] = bv; v[best] = -1e30f;
        }
        float e1 = __expf(val[1] - val[0]);
        float e2 = __expf(val[2] - val[0]);
        float inv = 1.f / (1.f + e1 + e2);
        float g[KTOP] = {inv, e1 * inv, e2 * inv};
#pragma unroll
        for (int k = 0; k < KTOP; k++) {
            top_idx[row * KTOP + k] = idx[k];
            top_gate[row * KTOP + k] = g[k];
        }
    }
}

// ---------------- hist: 16 blocks, ballot histogram, zero atomics ----------------
__global__ __launch_bounds__(256) void k_hist(
    const int* __restrict__ top_idx, int* __restrict__ partial) {
    __shared__ int wcnt[4][16];
    int t = threadIdx.x;
    int w = t >> 6, lane = t & 63;
    int blk = blockIdx.x;
    int cnt[16];
#pragma unroll
    for (int k = 0; k < 16; k++) cnt[k] = 0;
#pragma unroll
    for (int j = 0; j < 6; j++) {
        int e = top_idx[blk * 1536 + j * 256 + t];
#pragma unroll
        for (int k = 0; k < 16; k++)
            cnt[k] += (int)__popcll(__ballot(e == k));
    }
    if (lane == 0) {
#pragma unroll
        for (int k = 0; k < 16; k++) wcnt[w][k] = cnt[k];
    }
    __syncthreads();
    if (t < 16) partial[blk * 16 + t] = wcnt[0][t] + wcnt[1][t] + wcnt[2][t] + wcnt[3][t];
}

// ---------------- scan: counts, padded offsets, tile map, per-(block,expert) bases ----------------
__global__ __launch_bounds__(256) void k_scan(
    const int* __restrict__ partial, int* __restrict__ counts,
    int* __restrict__ tile_expert, int* __restrict__ gbase) {
    __shared__ int sp[HBLK * 16];
    __shared__ int soff[16];
    int t = threadIdx.x;
    sp[t] = partial[t];
    __syncthreads();
    if (t < 16) {
        int s = 0;
#pragma unroll
        for (int b = 0; b < HBLK; b++) s += sp[b * 16 + t];
        counts[t] = s;
    }
    __syncthreads();
    if (t == 0) {
        int off = 0;
        for (int e = 0; e < E_; e++) {
            int c = 0;
#pragma unroll
            for (int b = 0; b < HBLK; b++) c += sp[b * 16 + e];
            soff[e] = off;
            int pd = (c + 127) & ~127;
            int t0 = off >> 7, t1 = (off + pd) >> 7;
            for (int tt = t0; tt < t1; ++tt) tile_expert[tt] = e;
            off += pd;
        }
    }
    __syncthreads();
    {   // gbase[b][e] = soff[e] + sum_{b'<b} partial[b'][e]
        int b = t >> 4, e = t & 15;
        int s = soff[e];
        for (int bp = 0; bp < b; bp++) s += sp[bp * 16 + e];
        gbase[t] = s;
    }
}

// ---------------- scatter: LDS-rank only (zero global atomics), partial importance ----------------
__global__ __launch_bounds__(256) void k_scatter(
    const int* __restrict__ top_idx, const float* __restrict__ top_gate,
    const int* __restrict__ gbase,
    int* __restrict__ row_ids, int* __restrict__ rowslot,
    float* __restrict__ partial_imp) {
    __shared__ int lcnt[16];
    __shared__ float limp[16];
    int t = threadIdx.x;
    int blk = blockIdx.x;
    if (t < 16) { lcnt[t] = 0; limp[t] = 0.f; }
    __syncthreads();
#pragma unroll
    for (int j = 0; j < 6; j++) {
        int gid = blk * 1536 + j * 256 + t;
        int e = top_idx[gid];
        float g = top_gate[gid];
        int rank = atomicAdd(&lcnt[e], 1);
        atomicAdd(&limp[e], g);
        int slot = gbase[blk * 16 + e] + rank;
        row_ids[slot] = gid / KTOP;
        rowslot[gid] = slot;
    }
    __syncthreads();
    if (t < 16) partial_imp[blk * 16 + t] = limp[t];
}

// ======================= GEMMs: BK=64, XOR-swizzled LDS, 3 blocks/CU =======================
// LDS tile: 128 rows x 64k bf16 -> 8 chunks of 16B per row.
// LDS (row, p) holds global k-chunk p ^ (row&7); staging lane-contiguous.

// ---------------- GEMM1: h = relu(gather(x) @ W1[e] + b1[e]) -> bf16 ----------------
__global__ __launch_bounds__(256) void k_gemm1(
    const bf16* __restrict__ xbf, const bf16* __restrict__ w1t,
    const float* __restrict__ b1, const int* __restrict__ row_ids,
    const int* __restrict__ tile_expert, const bf16* __restrict__ zero_row,
    bf16* __restrict__ h) {
    int e = tile_expert[blockIdx.y];
    if (e < 0) return;
    int slot_base = blockIdx.y * 128;
    int nbase = blockIdx.x * 128;
    __shared__ __align__(16) bf16 As[128 * 64];  // 16 KB
    __shared__ __align__(16) bf16 Bs[128 * 64];  // 16 KB
    int t = threadIdx.x;
    int rmod = (t >> 3) & 7;
    int cglob = (t & 7) ^ rmod;
    const bf16* gA[4];
    const bf16* gB[4];
#pragma unroll
    for (int j = 0; j < 4; j++) {
        int m = j * 32 + (t >> 3);
        int rid = row_ids[slot_base + m];
        gA[j] = ((rid >= 0) ? xbf + (size_t)rid * IN_ : zero_row) + cglob * 8;
        gB[j] = w1t + ((size_t)e * H_ + nbase + m) * IN_ + cglob * 8;
    }
    int w = t >> 6, lane = t & 63;
    int wm = (w >> 1) * 64, wn = (w & 1) * 64;
    int lm = lane & 15, lq = lane >> 4;
    f32x4 acc[4][4] = {};
    for (int k0 = 0; k0 < IN_; k0 += 64) {
#pragma unroll
        for (int j = 0; j < 4; j++) {
            async16(gA[j] + k0, As + (j * 256 + t) * 8);
            async16(gB[j] + k0, Bs + (j * 256 + t) * 8);
        }
        __syncthreads();
        const bf16x8* Av = (const bf16x8*)As;
        const bf16x8* Bv = (const bf16x8*)Bs;
#pragma unroll
        for (int ks = 0; ks < 2; ks++) {
            int kc = ks * 4 + lq;
            bf16x8 af[4], bfv[4];
#pragma unroll
            for (int i = 0; i < 4; i++) {
                int row = wm + i * 16 + lm;
                af[i] = Av[row * 8 + (kc ^ (row & 7))];
            }
#pragma unroll
            for (int i = 0; i < 4; i++) {
                int row = wn + i * 16 + lm;
                bfv[i] = Bv[row * 8 + (kc ^ (row & 7))];
            }
#pragma unroll
            for (int mi = 0; mi < 4; mi++)
#pragma unroll
                for (int ni = 0; ni < 4; ni++)
                    acc[mi][ni] = __builtin_amdgcn_mfma_f32_16x16x32_bf16(af[mi], bfv[ni], acc[mi][ni], 0, 0, 0);
        }
        __syncthreads();
    }
#pragma unroll
    for (int mi = 0; mi < 4; mi++) {
#pragma unroll
        for (int ni = 0; ni < 4; ni++) {
            int colg = nbase + wn + ni * 16 + lm;
            float bias = b1[e * H_ + colg];
#pragma unroll
            for (int r = 0; r < 4; r++) {
                int rowl = wm + mi * 16 + lq * 4 + r;
                float v = acc[mi][ni][r] + bias;
                v = v > 0.f ? v : 0.f;
                h[(size_t)(slot_base + rowl) * H_ + colg] = (bf16)v;
            }
        }
    }
}

// ---------------- GEMM2: eout[slot] = h[slot] @ W2[e] + b2[e]  (f32) ----------------
__global__ __launch_bounds__(256) void k_gemm2(
    const bf16* __restrict__ h, const bf16* __restrict__ w2t,
    const float* __restrict__ b2, const int* __restrict__ tile_expert,
    float* __restrict__ eout) {
    int e = tile_expert[blockIdx.y];
    if (e < 0) return;
    int slot_base = blockIdx.y * 128;
    int nbase = blockIdx.x * 128;
    __shared__ __align__(16) bf16 As[128 * 64];
    __shared__ __align__(16) bf16 Bs[128 * 64];
    int t = threadIdx.x;
    int rmod = (t >> 3) & 7;
    int cglob = (t & 7) ^ rmod;
    const bf16* gA[4];
    const bf16* gB[4];
#pragma unroll
    for (int j = 0; j < 4; j++) {
        int m = j * 32 + (t >> 3);
        gA[j] = h + (size_t)(slot_base + m) * H_ + cglob * 8;
        gB[j] = w2t + ((size_t)e * OUT_ + nbase + m) * H_ + cglob * 8;
    }
    int w = t >> 6, lane = t & 63;
    int wm = (w >> 1) * 64, wn = (w & 1) * 64;
    int lm = lane & 15, lq = lane >> 4;
    f32x4 acc[4][4] = {};
    for (int k0 = 0; k0 < H_; k0 += 64) {
#pragma unroll
        for (int j = 0; j < 4; j++) {
            async16(gA[j] + k0, As + (j * 256 + t) * 8);
            async16(gB[j] + k0, Bs + (j * 256 + t) * 8);
        }
        __syncthreads();
        const bf16x8* Av = (const bf16x8*)As;
        const bf16x8* Bv = (const bf16x8*)Bs;
#pragma unroll
        for (int ks = 0; ks < 2; ks++) {
            int kc = ks * 4 + lq;
            bf16x8 af[4], bfv[4];
#pragma unroll
            for (int i = 0; i < 4; i++) {
                int row = wm + i * 16 + lm;
                af[i] = Av[row * 8 + (kc ^ (row & 7))];
            }
#pragma unroll
            for (int i = 0; i < 4; i++) {
                int row = wn + i * 16 + lm;
                bfv[i] = Bv[row * 8 + (kc ^ (row & 7))];
            }
#pragma unroll
            for (int mi = 0; mi < 4; mi++)
#pragma unroll
                for (int ni = 0; ni < 4; ni++)
                    acc[mi][ni] = __builtin_amdgcn_mfma_f32_16x16x32_bf16(af[mi], bfv[ni], acc[mi][ni], 0, 0, 0);
        }
        __syncthreads();
    }
#pragma unroll
    for (int mi = 0; mi < 4; mi++) {
#pragma unroll
        for (int ni = 0; ni < 4; ni++) {
            int colg = nbase + wn + ni * 16 + lm;
            float bias = b2[e * OUT_ + colg];
#pragma unroll
            for (int r = 0; r < 4; r++) {
                int rowl = wm + mi * 16 + lq * 4 + r;
                eout[(size_t)(slot_base + rowl) * OUT_ + colg] = acc[mi][ni][r] + bias;
            }
        }
    }
}

// ---------------- combine: y[b] = sum_k gate_k * eout[slot_k] ----------------
__global__ __launch_bounds__(256) void k_combine(
    const float* __restrict__ eout, const int* __restrict__ rowslot,
    const float* __restrict__ top_gate, float* __restrict__ y) {
    int t = threadIdx.x;
    int b = blockIdx.x * 4 + (t >> 6);
    int lane = t & 63;
    int s0 = rowslot[b * 3], s1 = rowslot[b * 3 + 1], s2 = rowslot[b * 3 + 2];
    float g0 = top_gate[b * 3], g1 = top_gate[b * 3 + 1], g2 = top_gate[b * 3 + 2];
    const float4* e4 = (const float4*)eout;
    float4 v0 = e4[(size_t)s0 * 64 + lane];
    float4 v1 = e4[(size_t)s1 * 64 + lane];
    float4 v2 = e4[(size_t)s2 * 64 + lane];
    float4 r;
    r.x = g0 * v0.x + g1 * v1.x + g2 * v2.x;
    r.y = g0 * v0.y + g1 * v1.y + g2 * v2.y;
    r.z = g0 * v0.z + g1 * v1.z + g2 * v2.z;
    r.w = g0 * v0.w + g1 * v1.w + g2 * v2.w;
    ((float4*)y)[(size_t)b * 64 + lane] = r;
}

// ---------------- loss: reduce partial importance, cv^2 (ddof=1) ----------------
__global__ void k_loss(const float* __restrict__ partial_imp, const int* __restrict__ counts,
                       float* __restrict__ loss_out) {
    __shared__ float imp[16];
    int t = threadIdx.x;
    if (t < 16) {
        float s = 0.f;
#pragma unroll
        for (int b = 0; b < HBLK; b++) s += partial_imp[b * 16 + t];
        imp[t] = s;
    }
    __syncthreads();
    if (t == 0) {
        float si = 0.f, sl = 0.f;
        for (int e = 0; e < E_; e++) { si += imp[e]; sl += (float)counts[e]; }
        float mi_ = si / (float)E_, ml_ = sl / (float)E_;
        float vi = 0.f, vl = 0.f;
        for (int e = 0; e < E_; e++) {
            float d = imp[e] - mi_; vi += d * d;
            float d2 = (float)counts[e] - ml_; vl += d2 * d2;
        }
        vi /= (float)(E_ - 1); vl /= (float)(E_ - 1);
        *loss_out = vi / (mi_ * mi_ + 1e-10f) + vl / (ml_ * ml_ + 1e-10f);
    }
}

extern "C" void kernel_launch(void* const* d_in, const int* in_sizes, int n_in,
                              void* d_out, int out_size, void* d_ws, size_t ws_size,
                              hipStream_t stream) {
    (void)in_sizes; (void)n_in; (void)out_size; (void)ws_size;
    const float* x = (const float*)d_in[0];
    const float* wgate = (const float*)d_in[1];
    const float* W1 = (const float*)d_in[2];
    const float* b1 = (const float*)d_in[3];
    const float* W2 = (const float*)d_in[4];
    const float* b2 = (const float*)d_in[5];
    float* y = (float*)d_out;  // [B*OUT] floats, then loss scalar at [B*OUT]

    char* p = (char*)d_ws;
    auto alloc = [&](size_t bytes) {
        char* q = p;
        p += (bytes + 255) & ~(size_t)255;
        return q;
    };
    bf16* xbf = (bf16*)alloc((size_t)B_ * IN_ * 2);          // 16 MB (dead after gemm1)
    bf16* w1t = (bf16*)alloc((size_t)E_ * H_ * IN_ * 2);     // 16 MB (dead after gemm1)
    bf16* w2t = (bf16*)alloc((size_t)E_ * OUT_ * H_ * 2);    // 4 MB
    bf16* h = (bf16*)alloc((size_t)MAXSLOTS * H_ * 2);       // 27 MB
    int* row_ids = (int*)alloc((size_t)MAXSLOTS * 4);
    int* rowslot = (int*)alloc((size_t)B_ * KTOP * 4);
    int* top_idx = (int*)alloc((size_t)B_ * KTOP * 4);
    float* top_gate = (float*)alloc((size_t)B_ * KTOP * 4);
    int* counts = (int*)alloc(E_ * 4);
    int* partial = (int*)alloc(HBLK * E_ * 4);
    int* gbase = (int*)alloc(HBLK * E_ * 4);
    float* partial_imp = (float*)alloc(HBLK * E_ * 4);
    int* tile_expert = (int*)alloc(NTILES * 4);
    bf16* zero_row = (bf16*)alloc(IN_ * 2);
    float* wgT = (float*)alloc((size_t)E_ * IN_ * 4);        // 64 KB
    // eout (27 MB f32) aliases xbf+w1t (32 MB): both dead after gemm1.
    float* eout = (float*)xbf;

    k_init<<<dim3((MAXSLOTS + 255) / 256), dim3(256), 0, stream>>>(
        row_ids, tile_expert, zero_row, wgate, wgT);
    k_transpose<<<dim3(2048 + 512), dim3(256), 0, stream>>>(W1, w1t, W2, w2t);
    k_gating<<<dim3(B_ / 4), dim3(256), 0, stream>>>(x, wgT, xbf, top_idx, top_gate);
    k_hist<<<dim3(HBLK), dim3(256), 0, stream>>>(top_idx, partial);
    k_scan<<<dim3(1), dim3(256), 0, stream>>>(partial, counts, tile_expert, gbase);
    k_scatter<<<dim3(HBLK), dim3(256), 0, stream>>>(
        top_idx, top_gate, gbase, row_ids, rowslot, partial_imp);
    k_gemm1<<<dim3(H_ / 128, NTILES), dim3(256), 0, stream>>>(
        xbf, w1t, b1, row_ids, tile_expert, zero_row, h);
    k_gemm2<<<dim3(OUT_ / 128, NTILES), dim3(256), 0, stream>>>(
        h, w2t, b2, tile_expert, eout);
    k_combine<<<dim3(B_ / 4), dim3(256), 0, stream>>>(eout, rowslot, top_gate, y);
    k_loss<<<dim3(1), dim3(64), 0, stream>>>(partial_imp, counts, y + (size_t)B_ * OUT_);
}